// Round 8
// baseline (32012.811 us; speedup 1.0000x reference)
//
#include <hip/hip_runtime.h>
#include <hip/hip_bf16.h>

#define SLEN 2048
#define BROWS 64
#define IDIM 512
#define HDIM 512
#define NWG 64
#define NTHREADS 768   // 12 waves: 8 recurrent + 4 producer

typedef __bf16 bf16x8 __attribute__((ext_vector_type(8)));
typedef float  f32x4  __attribute__((ext_vector_type(4)));
typedef int    i32x4  __attribute__((ext_vector_type(4)));
typedef int    i32x2  __attribute__((ext_vector_type(2)));

__device__ inline unsigned short f2bf(float f) {
  union { float f; unsigned u; } v; v.f = f;
  unsigned r = v.u + 0x7FFFu + ((v.u >> 16) & 1u);
  return (unsigned short)(r >> 16);
}
__device__ inline float sigm(float x) {
  return __builtin_amdgcn_rcpf(1.f + __expf(-x));
}
__device__ inline float tanh_f(float x) {
  float e = __expf(2.f * x);
  return 1.f - 2.f * __builtin_amdgcn_rcpf(e + 1.f);
}

// CT[row][k], row-major K=1024. row = w*128 + n*16 + gate*4 + hsub
//   where j = gate*512 + hcol, hcol = w*32 + n*4 + hsub
// k < 512: W[k][j] ; k >= 512: U[k-512][j]
__global__ __launch_bounds__(256) void prep_ct(const float* __restrict__ W,
                                               const float* __restrict__ U,
                                               unsigned short* __restrict__ CT) {
  int k = blockIdx.x;
  const float* src = (k < IDIM) ? (W + (size_t)k * 2048) : (U + (size_t)(k - IDIM) * 2048);
  for (int j = threadIdx.x; j < 2048; j += 256) {
    int gate = j >> 9, hcol = j & 511;
    int w = hcol >> 5, n = (hcol >> 2) & 7, hsub = hcol & 3;
    int row = w * 128 + n * 16 + gate * 4 + hsub;
    CT[(size_t)row * 1024 + k] = f2bf(src[j]);
  }
}

#define LOAD16(PTR, SC) \
  asm volatile( \
    "global_load_dwordx4 %0,  %16, off offset:0   " SC "\n\t" \
    "global_load_dwordx4 %1,  %16, off offset:64  " SC "\n\t" \
    "global_load_dwordx4 %2,  %16, off offset:128 " SC "\n\t" \
    "global_load_dwordx4 %3,  %16, off offset:192 " SC "\n\t" \
    "global_load_dwordx4 %4,  %16, off offset:256 " SC "\n\t" \
    "global_load_dwordx4 %5,  %16, off offset:320 " SC "\n\t" \
    "global_load_dwordx4 %6,  %16, off offset:384 " SC "\n\t" \
    "global_load_dwordx4 %7,  %16, off offset:448 " SC "\n\t" \
    "global_load_dwordx4 %8,  %16, off offset:512 " SC "\n\t" \
    "global_load_dwordx4 %9,  %16, off offset:576 " SC "\n\t" \
    "global_load_dwordx4 %10, %16, off offset:640 " SC "\n\t" \
    "global_load_dwordx4 %11, %16, off offset:704 " SC "\n\t" \
    "global_load_dwordx4 %12, %16, off offset:768 " SC "\n\t" \
    "global_load_dwordx4 %13, %16, off offset:832 " SC "\n\t" \
    "global_load_dwordx4 %14, %16, off offset:896 " SC "\n\t" \
    "global_load_dwordx4 %15, %16, off offset:960 " SC "\n\t" \
    "s_waitcnt vmcnt(0)" \
    : "=&v"(R[0]), "=&v"(R[1]), "=&v"(R[2]), "=&v"(R[3]), \
      "=&v"(R[4]), "=&v"(R[5]), "=&v"(R[6]), "=&v"(R[7]), \
      "=&v"(R[8]), "=&v"(R[9]), "=&v"(R[10]), "=&v"(R[11]), \
      "=&v"(R[12]), "=&v"(R[13]), "=&v"(R[14]), "=&v"(R[15]) \
    : "v"(PTR) : "memory")

__global__ __launch_bounds__(NTHREADS)
__attribute__((amdgpu_waves_per_eu(3, 3)))
void lstm_persist(const float* __restrict__ x, const float* __restrict__ bias,
                  const unsigned short* __restrict__ CT,
                  unsigned short* __restrict__ hG,    // [2][64][512] bf16
                  unsigned* __restrict__ flags,       // [4*16] on 64B stride
                  float* __restrict__ out) {
  const int bid  = blockIdx.x;
  const int g    = bid & 3;            // batch rows [16g, 16g+16)
  const int w    = bid >> 2;           // hcols [32w, 32w+32)
  const int tid  = threadIdx.x;
  const int lane = tid & 63;
  const int wid  = tid >> 6;           // 0..11
  const int lg   = lane >> 4;
  const int lc   = lane & 15;
  const bool isrec = wid < 8;
  const int n = wid;                   // rec tile 0..7 (hcols w*32+4n..+4)
  const int p = wid - 8;               // producer 0..3 (tiles 2p, 2p+1)

  __shared__ f32x4 ring[2][4][2][64];            // 16 KB xW+bias handoff
  __shared__ unsigned short stag[8][16][4];      // 1 KB h transpose staging
  __shared__ unsigned rcnt;

  if (tid == 0) rcnt = 0;

  // ---- rec U weights: ONE asm (loads + waitcnt) -> spill-safe, un-rematable ----
  i32x4 U[16];
  if (isrec) {
    const unsigned short* ub = CT + (size_t)(w * 128 + n * 16 + lc) * 1024 + 512 + lg * 8;
    { i32x4* R = U; LOAD16(ub, ""); }
  }

  float bias_v[2] = {0.f, 0.f};
  if (!isrec) {
    #pragma unroll
    for (int nt = 0; nt < 2; ++nt)
      bias_v[nt] = bias[(lc >> 2) * 512 + w * 32 + (2 * p + nt) * 4 + (lc & 3)];
  }

  const float* xbase = x + ((size_t)16 * g + lc) * IDIM + lg * 8;
  const unsigned short* ctw = CT + (size_t)(w * 128) * 1024;

  auto PROD = [&](int tt, int slot) {   // producers: plain loads, remat is fine
    f32x4 pa0 = {bias_v[0], bias_v[0], bias_v[0], bias_v[0]};
    f32x4 pa1 = {bias_v[1], bias_v[1], bias_v[1], bias_v[1]};
    const float* xp = xbase + (size_t)tt * (BROWS * IDIM);
    #pragma unroll
    for (int kk = 0; kk < 16; ++kk) {
      f32x4 v0 = *(const f32x4*)(xp + kk * 32);
      f32x4 v1 = *(const f32x4*)(xp + kk * 32 + 4);
      bf16x8 a;
      #pragma unroll
      for (int j = 0; j < 4; ++j) { a[j] = (__bf16)v0[j]; a[4 + j] = (__bf16)v1[j]; }
      bf16x8 b0 = *(const bf16x8*)(ctw + (size_t)((2 * p + 0) * 16 + lc) * 1024 + kk * 32 + lg * 8);
      bf16x8 b1 = *(const bf16x8*)(ctw + (size_t)((2 * p + 1) * 16 + lc) * 1024 + kk * 32 + lg * 8);
      pa0 = __builtin_amdgcn_mfma_f32_16x16x32_bf16(a, b0, pa0, 0, 0, 0);
      pa1 = __builtin_amdgcn_mfma_f32_16x16x32_bf16(a, b1, pa1, 0, 0, 0);
    }
    ring[slot][p][0][lane] = pa0;
    ring[slot][p][1][lane] = pa1;
  };

  if (!isrec) PROD(0, 0);
  __syncthreads();   // ring slot 0 + rcnt ready

  float cst[4] = {0.f, 0.f, 0.f, 0.f};
  const bool act = (lc < 4);               // lanes computing c/h (gate i cols)
  const int hcol = w * 32 + n * 4 + (lc & 3);
  const size_t HS = (size_t)SLEN * BROWS * HDIM;
  const unsigned short* apL = hG + ((size_t)16 * g + lc) * HDIM + lg * 8;

  for (int t = 0; t < SLEN; ++t) {
    if (isrec) {
      f32x4 acc = ring[t & 1][n >> 1][n & 1][lane];

      if (t > 0) {
        // ---- parallel poll: all rec waves watch the 16 group flags ----
        const unsigned* fp = flags + (size_t)(g * 16 + (lane & 15)) * 16;
        while (__ballot(__hip_atomic_load(fp, __ATOMIC_RELAXED,
                                          __HIP_MEMORY_SCOPE_AGENT)
                        >= (unsigned)t) != ~0ull) {}
        __builtin_amdgcn_sched_barrier(0);

        // ---- h(t-1): ONE asm, 16 loads + waitcnt (spill-safe) ----
        const unsigned short* ap = apL + (size_t)((t - 1) & 1) * (BROWS * HDIM);
        i32x4 A[16];
        { i32x4* R = A; LOAD16(ap, "sc0 sc1"); }
        __builtin_amdgcn_sched_barrier(0);

        #pragma unroll
        for (int kk = 0; kk < 16; ++kk) {
          union { i32x4 i; bf16x8 h; } ua, uu;
          ua.i = A[kk]; uu.i = U[kk];
          acc = __builtin_amdgcn_mfma_f32_16x16x32_bf16(ua.h, uu.h, acc, 0, 0, 0);
        }
      }

      // ---- gates -> c,h (cols: gate = lc>>2, hsub = lc&3) ----
      float hnv[4], cnv[4];
      #pragma unroll
      for (int reg = 0; reg < 4; ++reg) {
        float own = acc[reg];
        float g4  = __shfl_xor(own, 4, 64);
        float g8  = __shfl_xor(own, 8, 64);
        float g12 = __shfl_xor(own, 12, 64);
        // lanes lc<4: own=i, g4=f, g8=g, g12=o
        float it = sigm(own), ft = sigm(g4), gt = tanh_f(g8), ot = sigm(g12);
        float cn = ft * cst[reg] + it * gt;
        cst[reg] = cn;
        float hn = ot * tanh_f(cn);
        hnv[reg] = hn; cnv[reg] = cn;
        if (act) stag[n][4 * lg + reg][lc & 3] = f2bf(hn);
      }

      if (t + 1 < SLEN) {
        // ---- exchange store: 16 lanes x 8B ----
        if (lane < 16) {
          i32x2 hv = *(const i32x2*)&stag[n][lane][0];
          const unsigned short* d0 = hG + (size_t)(t & 1) * (BROWS * HDIM)
                                   + ((size_t)16 * g + lane) * HDIM + w * 32 + n * 4;
          asm volatile("global_store_dwordx2 %0, %1, off sc0 sc1"
                       :: "v"(d0), "v"(hv) : "memory");
        }
        asm volatile("s_waitcnt vmcnt(0)" ::: "memory");
        if (lane == 0)
          __hip_atomic_fetch_add(&rcnt, 1u, __ATOMIC_RELEASE,
                                 __HIP_MEMORY_SCOPE_WORKGROUP);
        if (wid == 0 && lane == 0) {
          while (__hip_atomic_load(&rcnt, __ATOMIC_ACQUIRE,
                                   __HIP_MEMORY_SCOPE_WORKGROUP) < 8u * (unsigned)(t + 1)) {}
          __hip_atomic_store(flags + (size_t)(g * 16 + w) * 16, (unsigned)(t + 1),
                             __ATOMIC_RELAXED, __HIP_MEMORY_SCOPE_AGENT);
        }
      }

      // ---- out writes AFTER the flag ----
      if (act) {
        #pragma unroll
        for (int reg = 0; reg < 4; ++reg) {
          size_t bglob = (size_t)16 * g + 4 * lg + reg;
          out[(size_t)t * (BROWS * HDIM) + bglob * HDIM + hcol] = hnv[reg];
          if (t == SLEN - 1) {
            out[HS + bglob * HDIM + hcol] = hnv[reg];
            out[HS + BROWS * HDIM + bglob * HDIM + hcol] = cnv[reg];
          }
        }
      }
    } else if (t + 1 < SLEN) {
      PROD(t + 1, (t + 1) & 1);
    }

    __syncthreads();   // ring slot handoff
  }
}

extern "C" void kernel_launch(void* const* d_in, const int* in_sizes, int n_in,
                              void* d_out, int out_size, void* d_ws, size_t ws_size,
                              hipStream_t stream) {
  const float* x    = (const float*)d_in[0];
  const float* W    = (const float*)d_in[1];
  const float* U    = (const float*)d_in[2];
  const float* bias = (const float*)d_in[3];
  float* out = (float*)d_out;

  unsigned short* CT = (unsigned short*)d_ws;                                    // 4 MiB
  unsigned short* hG = (unsigned short*)((char*)d_ws + (size_t)2048 * 1024 * 2); // 128 KiB
  unsigned* flags = (unsigned*)((char*)d_ws + (size_t)2048 * 1024 * 2
                                            + (size_t)2 * BROWS * HDIM * 2);     // 4 KiB

  hipMemsetAsync(flags, 0, 4 * 16 * 16 * sizeof(unsigned), stream);
  prep_ct<<<1024, 256, 0, stream>>>(W, U, CT);
  lstm_persist<<<NWG, NTHREADS, 0, stream>>>(x, bias, CT, hG, flags, out);
}

// Round 9
// 24741.016 us; speedup vs baseline: 1.2939x; 1.2939x over previous
//
#include <hip/hip_runtime.h>
#include <hip/hip_bf16.h>

#define SLEN 2048
#define BROWS 64
#define IDIM 512
#define HDIM 512
#define BH (BROWS * HDIM)
#define NWG 64
#define NTHREADS 768   // 12 waves: 8 recurrent + 4 producer
#define DYNPAD (96 * 1024)

typedef __bf16 bf16x8 __attribute__((ext_vector_type(8)));
typedef float  f32x4  __attribute__((ext_vector_type(4)));
typedef int    i32x4  __attribute__((ext_vector_type(4)));
typedef int    i32x2  __attribute__((ext_vector_type(2)));

__device__ inline unsigned short f2bf(float f) {
  union { float f; unsigned u; } v; v.f = f;
  unsigned r = v.u + 0x7FFFu + ((v.u >> 16) & 1u);
  return (unsigned short)(r >> 16);
}
__device__ inline float sigm(float x) {
  return __builtin_amdgcn_rcpf(1.f + __expf(-x));
}
__device__ inline float tanh_f(float x) {
  float e = __expf(2.f * x);
  return 1.f - 2.f * __builtin_amdgcn_rcpf(e + 1.f);
}

// CT[row][k], row-major K=1024. row = w*128 + n*16 + gate*4 + hsub
//   where j = gate*512 + hcol, hcol = w*32 + n*4 + hsub
// k < 512: W[k][j] ; k >= 512: U[k-512][j]
__global__ __launch_bounds__(256) void prep_ct(const float* __restrict__ W,
                                               const float* __restrict__ U,
                                               unsigned short* __restrict__ CT) {
  int k = blockIdx.x;
  const float* src = (k < IDIM) ? (W + (size_t)k * 2048) : (U + (size_t)(k - IDIM) * 2048);
  for (int j = threadIdx.x; j < 2048; j += 256) {
    int gate = j >> 9, hcol = j & 511;
    int w = hcol >> 5, n = (hcol >> 2) & 7, hsub = hcol & 3;
    int row = w * 128 + n * 16 + gate * 4 + hsub;
    CT[(size_t)row * 1024 + k] = f2bf(src[j]);
  }
}

#define LOAD16(PTR, SC) \
  asm volatile( \
    "global_load_dwordx4 %0,  %16, off offset:0   " SC "\n\t" \
    "global_load_dwordx4 %1,  %16, off offset:64  " SC "\n\t" \
    "global_load_dwordx4 %2,  %16, off offset:128 " SC "\n\t" \
    "global_load_dwordx4 %3,  %16, off offset:192 " SC "\n\t" \
    "global_load_dwordx4 %4,  %16, off offset:256 " SC "\n\t" \
    "global_load_dwordx4 %5,  %16, off offset:320 " SC "\n\t" \
    "global_load_dwordx4 %6,  %16, off offset:384 " SC "\n\t" \
    "global_load_dwordx4 %7,  %16, off offset:448 " SC "\n\t" \
    "global_load_dwordx4 %8,  %16, off offset:512 " SC "\n\t" \
    "global_load_dwordx4 %9,  %16, off offset:576 " SC "\n\t" \
    "global_load_dwordx4 %10, %16, off offset:640 " SC "\n\t" \
    "global_load_dwordx4 %11, %16, off offset:704 " SC "\n\t" \
    "global_load_dwordx4 %12, %16, off offset:768 " SC "\n\t" \
    "global_load_dwordx4 %13, %16, off offset:832 " SC "\n\t" \
    "global_load_dwordx4 %14, %16, off offset:896 " SC "\n\t" \
    "global_load_dwordx4 %15, %16, off offset:960 " SC "\n\t" \
    "s_waitcnt vmcnt(0)" \
    : "=&v"(R[0]), "=&v"(R[1]), "=&v"(R[2]), "=&v"(R[3]), \
      "=&v"(R[4]), "=&v"(R[5]), "=&v"(R[6]), "=&v"(R[7]), \
      "=&v"(R[8]), "=&v"(R[9]), "=&v"(R[10]), "=&v"(R[11]), \
      "=&v"(R[12]), "=&v"(R[13]), "=&v"(R[14]), "=&v"(R[15]) \
    : "v"(PTR) : "memory")

#define LOAD2(V0, V1, PTR) \
  asm volatile("global_load_dwordx4 %0, %2, off sc0 sc1\n\t" \
               "global_load_dwordx4 %1, %2, off offset:16 sc0 sc1\n\t" \
               "s_waitcnt vmcnt(0)" \
               : "=&v"(V0), "=&v"(V1) : "v"(PTR) : "memory")

__global__ __launch_bounds__(NTHREADS)
void lstm_persist(const float* __restrict__ x, const float* __restrict__ bias,
                  const unsigned short* __restrict__ CT,
                  unsigned short* __restrict__ hG,    // [2][64][512] bf16
                  unsigned* __restrict__ flags,       // [4*16] on 64B stride
                  float* __restrict__ out) {
  const int bid  = blockIdx.x;
  const int g    = bid & 3;            // batch rows [16g, 16g+16)
  const int w    = bid >> 2;           // hcols [32w, 32w+32)
  const int tid  = threadIdx.x;
  const int lane = tid & 63;
  const int wid  = tid >> 6;           // 0..11
  const int lg   = lane >> 4;
  const int lc   = lane & 15;
  const bool isrec = wid < 8;
  const int n = wid;                   // rec tile 0..7 (hcols w*32+4n..+4)
  const int p = wid - 8;               // producer 0..3 (tiles 2p, 2p+1)

  extern __shared__ char dynpad[];               // 96 KB: occupancy lever (1 WG/CU)
  __shared__ f32x4 ring[2][4][2][64];            // 16 KB xW+bias handoff
  __shared__ unsigned short Ast[16 * 512];       // 16 KB h(t-1) stage, swizzled
  __shared__ unsigned short stag[8][16][4];      // 1 KB h transpose staging
  __shared__ unsigned rcnt;
  (void)dynpad;

  if (tid == 0) rcnt = 0;

  // ---- rec U weights: ONE asm (loads + waitcnt), un-rematable; fits budget ----
  i32x4 U[16];
  if (isrec) {
    const unsigned short* ub = CT + (size_t)(w * 128 + n * 16 + lc) * 1024 + 512 + lg * 8;
    { i32x4* R = U; LOAD16(ub, ""); }
  }

  float bias_v[2] = {0.f, 0.f};
  if (!isrec) {
    #pragma unroll
    for (int nt = 0; nt < 2; ++nt)
      bias_v[nt] = bias[(lc >> 2) * 512 + w * 32 + (2 * p + nt) * 4 + (lc & 3)];
  }

  const float* xbase = x + ((size_t)16 * g + lc) * IDIM + lg * 8;
  const unsigned short* ctw = CT + (size_t)(w * 128) * 1024;

  auto PROD = [&](int tt, int slot) {   // producers: plain loads, remat is fine
    f32x4 pa0 = {bias_v[0], bias_v[0], bias_v[0], bias_v[0]};
    f32x4 pa1 = {bias_v[1], bias_v[1], bias_v[1], bias_v[1]};
    const float* xp = xbase + (size_t)tt * (BROWS * IDIM);
    #pragma unroll
    for (int kk = 0; kk < 16; ++kk) {
      f32x4 v0 = *(const f32x4*)(xp + kk * 32);
      f32x4 v1 = *(const f32x4*)(xp + kk * 32 + 4);
      bf16x8 a;
      #pragma unroll
      for (int j = 0; j < 4; ++j) { a[j] = (__bf16)v0[j]; a[4 + j] = (__bf16)v1[j]; }
      bf16x8 b0 = *(const bf16x8*)(ctw + (size_t)((2 * p + 0) * 16 + lc) * 1024 + kk * 32 + lg * 8);
      bf16x8 b1 = *(const bf16x8*)(ctw + (size_t)((2 * p + 1) * 16 + lc) * 1024 + kk * 32 + lg * 8);
      pa0 = __builtin_amdgcn_mfma_f32_16x16x32_bf16(a, b0, pa0, 0, 0, 0);
      pa1 = __builtin_amdgcn_mfma_f32_16x16x32_bf16(a, b1, pa1, 0, 0, 0);
    }
    ring[slot][p][0][lane] = pa0;
    ring[slot][p][1][lane] = pa1;
  };

  if (!isrec) PROD(0, 0);
  __syncthreads();   // ring slot 0 + rcnt ready

  float cst[4] = {0.f, 0.f, 0.f, 0.f};
  const bool act = (lc < 4);
  const int hcol = w * 32 + n * 4 + (lc & 3);
  const int sw = (lc & 7) << 4;
  const size_t HS = (size_t)SLEN * BROWS * HDIM;

  for (int t = 0; t < SLEN; ++t) {
    // ================= phase A: poll + stage | produce =================
    f32x4 acc;
    if (isrec) {
      acc = ring[t & 1][n >> 1][n & 1][lane];

      if (t > 0) {
        // parallel poll: all rec waves watch the 16 group flags
        const unsigned* fp = flags + (size_t)(g * 16 + (lane & 15)) * 16;
        while (__ballot(__hip_atomic_load(fp, __ATOMIC_RELAXED,
                                          __HIP_MEMORY_SCOPE_AGENT)
                        >= (unsigned)t) != ~0ull) {}
        __builtin_amdgcn_sched_barrier(0);

        // cooperative h(t-1) load -> swizzled Ast (32B/thread, 512 threads)
        {
          int idx0 = tid * 2;                 // 16B chunk id
          int r = idx0 >> 6, c16 = idx0 & 63;
          const unsigned short* gp = hG + (size_t)((t - 1) & 1) * BH
                                   + ((size_t)16 * g + r) * HDIM + c16 * 8;
          i32x4 v0, v1;
          LOAD2(v0, v1, gp);
          int rs = (r & 7) << 4;
          char* rowb = (char*)Ast + r * 1024;
          *(i32x4*)(rowb + ((c16 * 16) ^ rs)) = v0;
          *(i32x4*)(rowb + (((c16 + 1) * 16) ^ rs)) = v1;
        }
      }
    } else if (t + 1 < SLEN) {
      PROD(t + 1, (t + 1) & 1);
    }

    __syncthreads();   // Ast ready; ring[(t+1)&1] published

    // ================= phase B: recurrent GEMM + epilogue =================
    if (isrec) {
      if (t > 0) {
        const char* Ab = (const char*)Ast + (size_t)lc * 1024;
        #pragma unroll
        for (int kk = 0; kk < 16; ++kk) {
          int off = (kk * 64 + lg * 16) ^ sw;
          bf16x8 a = *(const bf16x8*)(Ab + off);
          union { i32x4 i; bf16x8 h; } uu;
          uu.i = U[kk];
          acc = __builtin_amdgcn_mfma_f32_16x16x32_bf16(a, uu.h, acc, 0, 0, 0);
        }
      }

      // gates -> c,h (cols: gate = lc>>2, hsub = lc&3)
      float hnv[4], cnv[4];
      #pragma unroll
      for (int reg = 0; reg < 4; ++reg) {
        float own = acc[reg];
        float g4  = __shfl_xor(own, 4, 64);
        float g8  = __shfl_xor(own, 8, 64);
        float g12 = __shfl_xor(own, 12, 64);
        float it = sigm(own), ft = sigm(g4), gt = tanh_f(g8), ot = sigm(g12);
        float cn = ft * cst[reg] + it * gt;
        cst[reg] = cn;
        float hn = ot * tanh_f(cn);
        hnv[reg] = hn; cnv[reg] = cn;
        if (act) stag[n][4 * lg + reg][lc & 3] = f2bf(hn);
      }

      if (t + 1 < SLEN) {
        // exchange store: 16 lanes x 8B, then flag release via LDS counter
        if (lane < 16) {
          i32x2 hv = *(const i32x2*)&stag[n][lane][0];
          const unsigned short* d0 = hG + (size_t)(t & 1) * BH
                                   + ((size_t)16 * g + lane) * HDIM + w * 32 + n * 4;
          asm volatile("global_store_dwordx2 %0, %1, off sc0 sc1"
                       :: "v"(d0), "v"(hv) : "memory");
        }
        asm volatile("s_waitcnt vmcnt(0)" ::: "memory");
        if (lane == 0)
          __hip_atomic_fetch_add(&rcnt, 1u, __ATOMIC_RELEASE,
                                 __HIP_MEMORY_SCOPE_WORKGROUP);
        if (wid == 0 && lane == 0) {
          while (__hip_atomic_load(&rcnt, __ATOMIC_ACQUIRE,
                                   __HIP_MEMORY_SCOPE_WORKGROUP) < 8u * (unsigned)(t + 1)) {}
          __hip_atomic_store(flags + (size_t)(g * 16 + w) * 16, (unsigned)(t + 1),
                             __ATOMIC_RELAXED, __HIP_MEMORY_SCOPE_AGENT);
        }
      }

      // out writes AFTER the flag (off the cross-WG critical path)
      if (act) {
        #pragma unroll
        for (int reg = 0; reg < 4; ++reg) {
          size_t bglob = (size_t)16 * g + 4 * lg + reg;
          out[(size_t)t * BH + bglob * HDIM + hcol] = hnv[reg];
          if (t == SLEN - 1) {
            out[HS + bglob * HDIM + hcol] = hnv[reg];
            out[HS + BH + bglob * HDIM + hcol] = cnv[reg];
          }
        }
      }
    }
  }
}

extern "C" void kernel_launch(void* const* d_in, const int* in_sizes, int n_in,
                              void* d_out, int out_size, void* d_ws, size_t ws_size,
                              hipStream_t stream) {
  const float* x    = (const float*)d_in[0];
  const float* W    = (const float*)d_in[1];
  const float* U    = (const float*)d_in[2];
  const float* bias = (const float*)d_in[3];
  float* out = (float*)d_out;

  unsigned short* CT = (unsigned short*)d_ws;                                    // 4 MiB
  unsigned short* hG = (unsigned short*)((char*)d_ws + (size_t)2048 * 1024 * 2); // 128 KiB
  unsigned* flags = (unsigned*)((char*)d_ws + (size_t)2048 * 1024 * 2
                                            + (size_t)2 * BH * 2);               // 4 KiB

  hipMemsetAsync(flags, 0, 4 * 16 * 16 * sizeof(unsigned), stream);
  prep_ct<<<1024, 256, 0, stream>>>(W, U, CT);
  lstm_persist<<<NWG, NTHREADS, DYNPAD, stream>>>(x, bias, CT, hG, flags, out);
}

// Round 10
// 14433.128 us; speedup vs baseline: 2.2180x; 1.7142x over previous
//
#include <hip/hip_runtime.h>
#include <hip/hip_bf16.h>

#define SLEN 2048
#define BROWS 64
#define IDIM 512
#define HDIM 512
#define BH (BROWS * HDIM)
#define RING 32
#define NREC 64
#define NWORK 192
#define NTOT 256
#define NTHREADS 512

typedef __bf16 bf16x8 __attribute__((ext_vector_type(8)));
typedef float  f32x4  __attribute__((ext_vector_type(4)));
typedef int    i32x4  __attribute__((ext_vector_type(4)));
typedef int    i32x2  __attribute__((ext_vector_type(2)));

__device__ inline unsigned short f2bf(float f) {
  union { float f; unsigned u; } v; v.f = f;
  unsigned r = v.u + 0x7FFFu + ((v.u >> 16) & 1u);
  return (unsigned short)(r >> 16);
}
__device__ inline float bf2f(unsigned short s) {
  union { unsigned u; float f; } v; v.u = ((unsigned)s) << 16;
  return v.f;
}
__device__ inline float sigm(float x) {
  return __builtin_amdgcn_rcpf(1.f + __expf(-x));
}
__device__ inline float tanh_f(float x) {
  float e = __expf(2.f * x);
  return 1.f - 2.f * __builtin_amdgcn_rcpf(e + 1.f);
}

// CT[row][k], row-major K=1024. row = w*128 + n*16 + gate*4 + hsub
//   where j = gate*512 + hcol, hcol = w*32 + n*4 + hsub
// k < 512: W[k][j] ; k >= 512: U[k-512][j]
__global__ __launch_bounds__(256) void prep_ct(const float* __restrict__ W,
                                               const float* __restrict__ U,
                                               unsigned short* __restrict__ CT) {
  int k = blockIdx.x;
  const float* src = (k < IDIM) ? (W + (size_t)k * 2048) : (U + (size_t)(k - IDIM) * 2048);
  for (int j = threadIdx.x; j < 2048; j += 256) {
    int gate = j >> 9, hcol = j & 511;
    int w = hcol >> 5, n = (hcol >> 2) & 7, hsub = hcol & 3;
    int row = w * 128 + n * 16 + gate * 4 + hsub;
    CT[(size_t)row * 1024 + k] = f2bf(src[j]);
  }
}

#define LOAD2(V0, V1, PTR) \
  asm volatile("global_load_dwordx4 %0, %2, off sc0 sc1\n\t" \
               "global_load_dwordx4 %1, %2, off offset:16 sc0 sc1\n\t" \
               "s_waitcnt vmcnt(0)" \
               : "=&v"(V0), "=&v"(V1) : "v"(PTR) : "memory")

__global__ __launch_bounds__(NTHREADS)
void lstm_fused(const float* __restrict__ x, const float* __restrict__ bias,
                const unsigned short* __restrict__ CT,
                unsigned short* __restrict__ gring,  // [RING][64][2048] bf16
                unsigned short* __restrict__ hG,     // [2][64][512] bf16
                unsigned* __restrict__ flags,        // [4*16] stride-16 dwords
                unsigned* __restrict__ flags2,       // [RING*16] stride-16 dwords
                float* __restrict__ out) {
  const int bid  = blockIdx.x;
  const int tid  = threadIdx.x;
  const int lane = tid & 63;
  const int wid  = tid >> 6;           // 0..7
  const int lg   = lane >> 4;
  const int lc   = lane & 15;

  extern __shared__ char Udyn[];       // 128 KB: rec U slice (swizzled)
  __shared__ union {
    struct {
      unsigned short Ast[16 * 512];    // 16 KB h(t-1), swizzled
      unsigned short Gst[16 * 128];    // 4 KB gates_x slice
      unsigned short stag[8][16][4];   // 1 KB h transpose staging
    } r;
    unsigned short Gout[64 * 128];     // 16 KB worker gate staging
  } sm;
  __shared__ unsigned rcnt;

  // ================================================================
  // WORKER PATH: x@W + bias -> gring (bf16), striped over t
  // ================================================================
  if (bid >= NREC) {
    const int wid2 = bid - NREC;
    const int w2 = wid2 & 15;          // col split: gate-cols [128*w2, +128)
    const int s  = wid2 >> 4;          // t stripe 0..11
    const int rt = wid & 3;            // row tile: batch rows [16*rt, +16)
    const int ch = wid >> 2;           // col half: tiles 4*ch..4*ch+3

    float bias_v[4];
    #pragma unroll
    for (int c4 = 0; c4 < 4; ++c4) {
      int n2 = 4 * ch + c4;
      bias_v[c4] = bias[(lc >> 2) * 512 + w2 * 32 + n2 * 4 + (lc & 3)];
    }

    for (int t = s; t < SLEN; t += 12) {
      if (t >= RING) {   // backpressure: consumers must have finished t-RING+1
        unsigned need = (unsigned)(t - RING + 2);
        const unsigned* bp = flags + (size_t)((lane & 3) * 16 + w2) * 16;
        while (__ballot((lane < 4) &&
                        (__hip_atomic_load(bp, __ATOMIC_RELAXED,
                                           __HIP_MEMORY_SCOPE_AGENT) < need)) != 0ull)
          __builtin_amdgcn_s_sleep(8);
      }

      f32x4 acc[4];
      #pragma unroll
      for (int c4 = 0; c4 < 4; ++c4)
        acc[c4] = (f32x4){bias_v[c4], bias_v[c4], bias_v[c4], bias_v[c4]};

      const float* xp = x + ((size_t)t * BROWS + 16 * rt + lc) * IDIM + lg * 8;
      #pragma unroll
      for (int kk = 0; kk < 16; ++kk) {
        f32x4 v0 = *(const f32x4*)(xp + kk * 32);
        f32x4 v1 = *(const f32x4*)(xp + kk * 32 + 4);
        bf16x8 a;
        #pragma unroll
        for (int j = 0; j < 4; ++j) { a[j] = (__bf16)v0[j]; a[4 + j] = (__bf16)v1[j]; }
        #pragma unroll
        for (int c4 = 0; c4 < 4; ++c4) {
          const bf16x8 b = *(const bf16x8*)(CT + (size_t)(w2 * 128 + (4 * ch + c4) * 16 + lc) * 1024
                                            + kk * 32 + lg * 8);
          acc[c4] = __builtin_amdgcn_mfma_f32_16x16x32_bf16(a, b, acc[c4], 0, 0, 0);
        }
      }

      // stage to LDS
      #pragma unroll
      for (int c4 = 0; c4 < 4; ++c4)
        #pragma unroll
        for (int reg = 0; reg < 4; ++reg)
          sm.Gout[(size_t)(16 * rt + 4 * lg + reg) * 128 + (4 * ch + c4) * 16 + lc]
            = f2bf(acc[c4][reg]);
      __syncthreads();

      // coop store 16 KB -> ring slot (32B/thread, coalesced)
      {
        int row = tid >> 3, cs = (tid & 7) * 16;          // 16 shorts = 32B
        const unsigned short* srcp = sm.Gout + (size_t)row * 128 + cs;
        i32x4 v0 = *(const i32x4*)srcp;
        i32x4 v1 = *(const i32x4*)(srcp + 8);
        unsigned short* d = gring + (size_t)(t & (RING - 1)) * (BROWS * 2048)
                          + (size_t)row * 2048 + w2 * 128 + cs;
        asm volatile("global_store_dwordx4 %0, %1, off sc0 sc1" :: "v"(d), "v"(v0) : "memory");
        asm volatile("global_store_dwordx4 %0, %1, off offset:16 sc0 sc1" :: "v"(d), "v"(v1) : "memory");
        asm volatile("s_waitcnt vmcnt(0)" ::: "memory");
      }
      __syncthreads();   // all threads drained -> flag release + Gout reuse safe
      if (tid == 0)
        __hip_atomic_store(flags2 + (size_t)((t & (RING - 1)) * 16 + w2) * 16,
                           (unsigned)(t + 1), __ATOMIC_RELAXED, __HIP_MEMORY_SCOPE_AGENT);
    }
    return;
  }

  // ================================================================
  // RECURRENT PATH: 64 WGs, 8 waves each, h@U from LDS weights
  // ================================================================
  const int g = bid & 3;               // batch rows [16g, 16g+16)
  const int w = bid >> 2;              // hcols [32w, 32w+32)
  const int n = wid;                   // col tile 0..7 (gate-cols n*16..+16)

  // cooperative U -> dynamic LDS (swizzled), 256B/thread
  #pragma unroll
  for (int i = 0; i < 16; ++i) {
    int idx16 = tid + NTHREADS * i;    // 0..8191
    int r = idx16 >> 6, c16 = idx16 & 63;
    i32x4 v = *(const i32x4*)(CT + (size_t)(w * 128 + r) * 1024 + 512 + c16 * 8);
    *(i32x4*)(Udyn + (size_t)r * 1024 + ((c16 * 16) ^ ((r & 7) << 4))) = v;
  }
  if (tid == 0) rcnt = 0;
  __syncthreads();

  float cst[4] = {0.f, 0.f, 0.f, 0.f};
  const bool act = (lc < 4);
  const int hcol = w * 32 + n * 4 + (lc & 3);
  const int sw = (lc & 7) << 4;
  const size_t HS = (size_t)SLEN * BH;

  for (int t = 0; t < SLEN; ++t) {
    // ---- combined poll: h-flags (lanes 0-15) + gates flag (all lanes) ----
    {
      const unsigned* fpH = flags + (size_t)(g * 16 + (lane & 15)) * 16;
      const unsigned* fpG = flags2 + (size_t)((t & (RING - 1)) * 16 + w) * 16;
      int notok;
      do {
        unsigned vH = __hip_atomic_load(fpH, __ATOMIC_RELAXED, __HIP_MEMORY_SCOPE_AGENT);
        unsigned vG = __hip_atomic_load(fpG, __ATOMIC_RELAXED, __HIP_MEMORY_SCOPE_AGENT);
        int okH = (lane >= 16) || (t == 0) || (vH >= (unsigned)t);
        notok = !(okH && (vG > (unsigned)t));
      } while (__ballot(notok) != 0ull);
    }
    __builtin_amdgcn_sched_barrier(0);

    // ---- coop loads: h(t-1) -> Ast (swizzled), gates -> Gst ----
    if (t > 0) {
      int idx0 = tid * 2;
      int r = idx0 >> 6, c16 = idx0 & 63;
      const unsigned short* gp = hG + (size_t)((t - 1) & 1) * BH
                               + ((size_t)16 * g + r) * HDIM + c16 * 8;
      i32x4 v0, v1;
      LOAD2(v0, v1, gp);
      int rs = (r & 7) << 4;
      char* rowb = (char*)sm.r.Ast + r * 1024;
      *(i32x4*)(rowb + ((c16 * 16) ^ rs)) = v0;
      *(i32x4*)(rowb + (((c16 + 1) * 16) ^ rs)) = v1;
    }
    {
      int row = tid >> 5, cs = (tid & 31) * 4;            // 4 shorts = 8B
      const unsigned short* gp = gring + (size_t)(t & (RING - 1)) * (BROWS * 2048)
                               + ((size_t)16 * g + row) * 2048 + w * 128 + cs;
      i32x2 v;
      asm volatile("global_load_dwordx2 %0, %1, off sc0 sc1\n\ts_waitcnt vmcnt(0)"
                   : "=&v"(v) : "v"(gp) : "memory");
      *(i32x2*)(sm.r.Gst + (size_t)row * 128 + cs) = v;
    }
    __syncthreads();

    // ---- GEMM: acc = gates_x + h @ U  (all from LDS) ----
    f32x4 acc;
    #pragma unroll
    for (int reg = 0; reg < 4; ++reg)
      acc[reg] = bf2f(sm.r.Gst[(size_t)(4 * lg + reg) * 128 + n * 16 + lc]);

    if (t > 0) {
      const char* Ab = (const char*)sm.r.Ast + (size_t)lc * 1024;
      const char* Bb = Udyn + (size_t)(n * 16 + lc) * 1024;
      #pragma unroll
      for (int kk = 0; kk < 16; ++kk) {
        int koff = kk * 64 + lg * 16;
        bf16x8 a = *(const bf16x8*)(Ab + (koff ^ sw));
        bf16x8 b = *(const bf16x8*)(Bb + (koff ^ sw));
        acc = __builtin_amdgcn_mfma_f32_16x16x32_bf16(a, b, acc, 0, 0, 0);
      }
    }

    // ---- gates -> c,h (gate = lc>>2, hsub = lc&3) ----
    float hnv[4], cnv[4];
    #pragma unroll
    for (int reg = 0; reg < 4; ++reg) {
      float own = acc[reg];
      float g4  = __shfl_xor(own, 4, 64);
      float g8  = __shfl_xor(own, 8, 64);
      float g12 = __shfl_xor(own, 12, 64);
      float it = sigm(own), ft = sigm(g4), gt = tanh_f(g8), ot = sigm(g12);
      float cn = ft * cst[reg] + it * gt;
      cst[reg] = cn;
      float hn = ot * tanh_f(cn);
      hnv[reg] = hn; cnv[reg] = cn;
      if (act) sm.r.stag[n][4 * lg + reg][lc & 3] = f2bf(hn);
    }

    if (t + 1 < SLEN) {
      // exchange store: 16 lanes x 8B (full 64B lines per 8-wave set)
      if (lane < 16) {
        i32x2 hv = *(const i32x2*)&sm.r.stag[n][lane][0];
        const unsigned short* d0 = hG + (size_t)(t & 1) * BH
                                 + ((size_t)16 * g + lane) * HDIM + w * 32 + n * 4;
        asm volatile("global_store_dwordx2 %0, %1, off sc0 sc1"
                     :: "v"(d0), "v"(hv) : "memory");
      }
      asm volatile("s_waitcnt vmcnt(0)" ::: "memory");
      if (lane == 0)
        __hip_atomic_fetch_add(&rcnt, 1u, __ATOMIC_RELEASE, __HIP_MEMORY_SCOPE_WORKGROUP);
      if (wid == 0 && lane == 0) {
        while (__hip_atomic_load(&rcnt, __ATOMIC_ACQUIRE,
                                 __HIP_MEMORY_SCOPE_WORKGROUP) < 8u * (unsigned)(t + 1)) {}
        __hip_atomic_store(flags + (size_t)(g * 16 + w) * 16, (unsigned)(t + 1),
                           __ATOMIC_RELAXED, __HIP_MEMORY_SCOPE_AGENT);
      }
    }

    // out writes AFTER the flag (off the cross-WG critical path)
    if (act) {
      #pragma unroll
      for (int reg = 0; reg < 4; ++reg) {
        size_t bglob = (size_t)16 * g + 4 * lg + reg;
        out[(size_t)t * BH + bglob * HDIM + hcol] = hnv[reg];
        if (t == SLEN - 1) {
          out[HS + bglob * HDIM + hcol] = hnv[reg];
          out[HS + BH + bglob * HDIM + hcol] = cnv[reg];
        }
      }
    }
  }
}

extern "C" void kernel_launch(void* const* d_in, const int* in_sizes, int n_in,
                              void* d_out, int out_size, void* d_ws, size_t ws_size,
                              hipStream_t stream) {
  const float* x    = (const float*)d_in[0];
  const float* W    = (const float*)d_in[1];
  const float* U    = (const float*)d_in[2];
  const float* bias = (const float*)d_in[3];
  float* out = (float*)d_out;

  char* p = (char*)d_ws;
  unsigned short* CT    = (unsigned short*)p;                      p += (size_t)2048 * 1024 * 2;  // 4 MiB
  unsigned short* gring = (unsigned short*)p;                      p += (size_t)RING * BROWS * 2048 * 2; // 8 MiB
  unsigned short* hG    = (unsigned short*)p;                      p += (size_t)2 * BH * 2;       // 128 KiB
  unsigned* flags  = (unsigned*)p;                                 p += 4 * 16 * 16 * 4;          // 4 KiB
  unsigned* flags2 = (unsigned*)p;                                                               // 32 KiB

  hipMemsetAsync(flags, 0, (4 * 16 + RING * 16) * 16 * sizeof(unsigned), stream);
  prep_ct<<<1024, 256, 0, stream>>>(W, U, CT);
  lstm_fused<<<NTOT, NTHREADS, 128 * 1024, stream>>>(x, bias, CT, gring, hG, flags, flags2, out);
}

// Round 11
// 13409.039 us; speedup vs baseline: 2.3874x; 1.0764x over previous
//
#include <hip/hip_runtime.h>
#include <hip/hip_bf16.h>

#define SLEN 2048
#define BROWS 64
#define IDIM 512
#define HDIM 512
#define BH (BROWS * HDIM)
#define RING 32
#define NREC 64
#define NWORK 192
#define NTOT 256
#define NTHREADS 512

typedef __bf16 bf16x8 __attribute__((ext_vector_type(8)));
typedef float  f32x4  __attribute__((ext_vector_type(4)));
typedef int    i32x4  __attribute__((ext_vector_type(4)));
typedef int    i32x2  __attribute__((ext_vector_type(2)));

__device__ inline unsigned short f2bf(float f) {
  union { float f; unsigned u; } v; v.f = f;
  unsigned r = v.u + 0x7FFFu + ((v.u >> 16) & 1u);
  return (unsigned short)(r >> 16);
}
__device__ inline float bf2f(unsigned short s) {
  union { unsigned u; float f; } v; v.u = ((unsigned)s) << 16;
  return v.f;
}
__device__ inline float sigm(float x) {
  return __builtin_amdgcn_rcpf(1.f + __expf(-x));
}
__device__ inline float tanh_f(float x) {
  float e = __expf(2.f * x);
  return 1.f - 2.f * __builtin_amdgcn_rcpf(e + 1.f);
}

// CT[row][k], row-major K=1024. row = w*128 + n*16 + gate*4 + hsub
//   where j = gate*512 + hcol, hcol = w*32 + n*4 + hsub
// k < 512: W[k][j] ; k >= 512: U[k-512][j]
__global__ __launch_bounds__(256) void prep_ct(const float* __restrict__ W,
                                               const float* __restrict__ U,
                                               unsigned short* __restrict__ CT) {
  int k = blockIdx.x;
  const float* src = (k < IDIM) ? (W + (size_t)k * 2048) : (U + (size_t)(k - IDIM) * 2048);
  for (int j = threadIdx.x; j < 2048; j += 256) {
    int gate = j >> 9, hcol = j & 511;
    int w = hcol >> 5, n = (hcol >> 2) & 7, hsub = hcol & 3;
    int row = w * 128 + n * 16 + gate * 4 + hsub;
    CT[(size_t)row * 1024 + k] = f2bf(src[j]);
  }
}

// Device-scope (IF-coherent) paired load: sc1 ONLY (sc0 sc1 = SYSTEM = HBM!)
#define LOAD2(V0, V1, PTR) \
  asm volatile("global_load_dwordx4 %0, %2, off sc1\n\t" \
               "global_load_dwordx4 %1, %2, off offset:16 sc1\n\t" \
               "s_waitcnt vmcnt(0)" \
               : "=&v"(V0), "=&v"(V1) : "v"(PTR) : "memory")

__global__ __launch_bounds__(NTHREADS)
void lstm_fused(const float* __restrict__ x, const float* __restrict__ bias,
                const unsigned short* __restrict__ CT,
                unsigned short* __restrict__ gring,  // [RING][64][2048] bf16
                unsigned short* __restrict__ hG,     // [2][64][512] bf16
                unsigned* __restrict__ flags,        // [4*16] stride-16 dwords
                unsigned* __restrict__ flags2,       // [RING*16] stride-16 dwords
                float* __restrict__ out) {
  const int bid  = blockIdx.x;
  const int tid  = threadIdx.x;
  const int lane = tid & 63;
  const int wid  = tid >> 6;           // 0..7
  const int lg   = lane >> 4;
  const int lc   = lane & 15;

  extern __shared__ char Udyn[];       // 128 KB: rec U slice (swizzled)
  __shared__ union {
    struct {
      unsigned short Ast[16 * 512];    // 16 KB h(t-1), swizzled
      unsigned short Gst[16 * 128];    // 4 KB gates_x slice
      unsigned short stag[8][16][4];   // 1 KB h transpose staging
    } r;
    unsigned short Gout[64 * 128];     // 16 KB worker gate staging
  } sm;
  __shared__ unsigned rcnt;

  // ================================================================
  // WORKER PATH: x@W + bias -> gring (bf16), striped over t
  // ================================================================
  if (bid >= NREC) {
    const int wid2 = bid - NREC;
    const int w2 = wid2 & 15;          // col split: gate-cols [128*w2, +128)
    const int s  = wid2 >> 4;          // t stripe 0..11
    const int rt = wid & 3;            // row tile: batch rows [16*rt, +16)
    const int ch = wid >> 2;           // col half: tiles 4*ch..4*ch+3

    float bias_v[4];
    #pragma unroll
    for (int c4 = 0; c4 < 4; ++c4) {
      int n2 = 4 * ch + c4;
      bias_v[c4] = bias[(lc >> 2) * 512 + w2 * 32 + n2 * 4 + (lc & 3)];
    }

    for (int t = s; t < SLEN; t += 12) {
      if (t >= RING) {   // backpressure: consumers must have finished t-RING+1
        unsigned need = (unsigned)(t - RING + 2);
        const unsigned* bp = flags + (size_t)((lane & 3) * 16 + w2) * 16;
        while (__ballot((lane < 4) &&
                        (__hip_atomic_load(bp, __ATOMIC_RELAXED,
                                           __HIP_MEMORY_SCOPE_AGENT) < need)) != 0ull)
          __builtin_amdgcn_s_sleep(8);
      }

      f32x4 acc[4];
      #pragma unroll
      for (int c4 = 0; c4 < 4; ++c4)
        acc[c4] = (f32x4){bias_v[c4], bias_v[c4], bias_v[c4], bias_v[c4]};

      const float* xp = x + ((size_t)t * BROWS + 16 * rt + lc) * IDIM + lg * 8;
      #pragma unroll
      for (int kk = 0; kk < 16; ++kk) {
        f32x4 v0 = *(const f32x4*)(xp + kk * 32);
        f32x4 v1 = *(const f32x4*)(xp + kk * 32 + 4);
        bf16x8 a;
        #pragma unroll
        for (int j = 0; j < 4; ++j) { a[j] = (__bf16)v0[j]; a[4 + j] = (__bf16)v1[j]; }
        #pragma unroll
        for (int c4 = 0; c4 < 4; ++c4) {
          const bf16x8 b = *(const bf16x8*)(CT + (size_t)(w2 * 128 + (4 * ch + c4) * 16 + lc) * 1024
                                            + kk * 32 + lg * 8);
          acc[c4] = __builtin_amdgcn_mfma_f32_16x16x32_bf16(a, b, acc[c4], 0, 0, 0);
        }
      }

      // stage to LDS
      #pragma unroll
      for (int c4 = 0; c4 < 4; ++c4)
        #pragma unroll
        for (int reg = 0; reg < 4; ++reg)
          sm.Gout[(size_t)(16 * rt + 4 * lg + reg) * 128 + (4 * ch + c4) * 16 + lc]
            = f2bf(acc[c4][reg]);
      __syncthreads();

      // coop store 16 KB -> ring slot (32B/thread, device scope)
      {
        int row = tid >> 3, cs = (tid & 7) * 16;          // 16 shorts = 32B
        const unsigned short* srcp = sm.Gout + (size_t)row * 128 + cs;
        i32x4 v0 = *(const i32x4*)srcp;
        i32x4 v1 = *(const i32x4*)(srcp + 8);
        unsigned short* d = gring + (size_t)(t & (RING - 1)) * (BROWS * 2048)
                          + (size_t)row * 2048 + w2 * 128 + cs;
        asm volatile("global_store_dwordx4 %0, %1, off sc1" :: "v"(d), "v"(v0) : "memory");
        asm volatile("global_store_dwordx4 %0, %1, off offset:16 sc1" :: "v"(d), "v"(v1) : "memory");
        asm volatile("s_waitcnt vmcnt(0)" ::: "memory");
      }
      __syncthreads();   // all threads drained -> flag release + Gout reuse safe
      if (tid == 0)
        __hip_atomic_store(flags2 + (size_t)((t & (RING - 1)) * 16 + w2) * 16,
                           (unsigned)(t + 1), __ATOMIC_RELAXED, __HIP_MEMORY_SCOPE_AGENT);
    }
    return;
  }

  // ================================================================
  // RECURRENT PATH: 64 WGs, 8 waves each, h@U from LDS weights
  // ================================================================
  const int g = bid & 3;               // batch rows [16g, 16g+16)
  const int w = bid >> 2;              // hcols [32w, 32w+32)
  const int n = wid;                   // col tile 0..7 (gate-cols n*16..+16)

  // cooperative U -> dynamic LDS (swizzled), 256B/thread
  #pragma unroll
  for (int i = 0; i < 16; ++i) {
    int idx16 = tid + NTHREADS * i;    // 0..8191
    int r = idx16 >> 6, c16 = idx16 & 63;
    i32x4 v = *(const i32x4*)(CT + (size_t)(w * 128 + r) * 1024 + 512 + c16 * 8);
    *(i32x4*)(Udyn + (size_t)r * 1024 + ((c16 * 16) ^ ((r & 7) << 4))) = v;
  }
  if (tid == 0) rcnt = 0;
  __syncthreads();

  float cst[4] = {0.f, 0.f, 0.f, 0.f};
  const bool act = (lc < 4);
  const int hcol = w * 32 + n * 4 + (lc & 3);
  const int sw = (lc & 7) << 4;
  const size_t HS = (size_t)SLEN * BH;

  for (int t = 0; t < SLEN; ++t) {
    // ---- phase 1: gates_x first (workers run ahead -> usually no wait) ----
    {
      const unsigned* fpG = flags2 + (size_t)((t & (RING - 1)) * 16 + w) * 16;
      while (__ballot(__hip_atomic_load(fpG, __ATOMIC_RELAXED,
                                        __HIP_MEMORY_SCOPE_AGENT)
                      <= (unsigned)t) != 0ull) {}
    }
    {
      int row = tid >> 5, cs = (tid & 31) * 4;            // 4 shorts = 8B
      const unsigned short* gp = gring + (size_t)(t & (RING - 1)) * (BROWS * 2048)
                               + ((size_t)16 * g + row) * 2048 + w * 128 + cs;
      i32x2 v;
      asm volatile("global_load_dwordx2 %0, %1, off sc1\n\ts_waitcnt vmcnt(0)"
                   : "=&v"(v) : "v"(gp) : "memory");
      *(i32x2*)(sm.r.Gst + (size_t)row * 128 + cs) = v;
    }

    // ---- phase 2: h-flags poll + h(t-1) coop load -> Ast (swizzled) ----
    if (t > 0) {
      const unsigned* fpH = flags + (size_t)(g * 16 + (lane & 15)) * 16;
      while (__ballot((lane < 16) &&
                      (__hip_atomic_load(fpH, __ATOMIC_RELAXED,
                                         __HIP_MEMORY_SCOPE_AGENT) < (unsigned)t)) != 0ull) {}
      __builtin_amdgcn_sched_barrier(0);

      int idx0 = tid * 2;
      int r = idx0 >> 6, c16 = idx0 & 63;
      const unsigned short* gp = hG + (size_t)((t - 1) & 1) * BH
                               + ((size_t)16 * g + r) * HDIM + c16 * 8;
      i32x4 v0, v1;
      LOAD2(v0, v1, gp);
      int rs = (r & 7) << 4;
      char* rowb = (char*)sm.r.Ast + r * 1024;
      *(i32x4*)(rowb + ((c16 * 16) ^ rs)) = v0;
      *(i32x4*)(rowb + (((c16 + 1) * 16) ^ rs)) = v1;
    }
    __syncthreads();

    // ---- GEMM: acc = gates_x + h @ U  (all from LDS) ----
    f32x4 acc;
    #pragma unroll
    for (int reg = 0; reg < 4; ++reg)
      acc[reg] = bf2f(sm.r.Gst[(size_t)(4 * lg + reg) * 128 + n * 16 + lc]);

    if (t > 0) {
      const char* Ab = (const char*)sm.r.Ast + (size_t)lc * 1024;
      const char* Bb = Udyn + (size_t)(n * 16 + lc) * 1024;
      #pragma unroll
      for (int kk = 0; kk < 16; ++kk) {
        int koff = kk * 64 + lg * 16;
        bf16x8 a = *(const bf16x8*)(Ab + (koff ^ sw));
        bf16x8 b = *(const bf16x8*)(Bb + (koff ^ sw));
        acc = __builtin_amdgcn_mfma_f32_16x16x32_bf16(a, b, acc, 0, 0, 0);
      }
    }

    // ---- gates -> c,h (gate = lc>>2, hsub = lc&3) ----
    float hnv[4], cnv[4];
    #pragma unroll
    for (int reg = 0; reg < 4; ++reg) {
      float own = acc[reg];
      float g4  = __shfl_xor(own, 4, 64);
      float g8  = __shfl_xor(own, 8, 64);
      float g12 = __shfl_xor(own, 12, 64);
      float it = sigm(own), ft = sigm(g4), gt = tanh_f(g8), ot = sigm(g12);
      float cn = ft * cst[reg] + it * gt;
      cst[reg] = cn;
      float hn = ot * tanh_f(cn);
      hnv[reg] = hn; cnv[reg] = cn;
      if (act) sm.r.stag[n][4 * lg + reg][lc & 3] = f2bf(hn);
    }

    if (t + 1 < SLEN) {
      // exchange store: 16 lanes x 8B (device scope), then flag via LDS counter
      if (lane < 16) {
        i32x2 hv = *(const i32x2*)&sm.r.stag[n][lane][0];
        const unsigned short* d0 = hG + (size_t)(t & 1) * BH
                                 + ((size_t)16 * g + lane) * HDIM + w * 32 + n * 4;
        asm volatile("global_store_dwordx2 %0, %1, off sc1"
                     :: "v"(d0), "v"(hv) : "memory");
      }
      asm volatile("s_waitcnt vmcnt(0)" ::: "memory");
      if (lane == 0)
        __hip_atomic_fetch_add(&rcnt, 1u, __ATOMIC_RELEASE, __HIP_MEMORY_SCOPE_WORKGROUP);
      if (wid == 0 && lane == 0) {
        while (__hip_atomic_load(&rcnt, __ATOMIC_ACQUIRE,
                                 __HIP_MEMORY_SCOPE_WORKGROUP) < 8u * (unsigned)(t + 1)) {}
        __hip_atomic_store(flags + (size_t)(g * 16 + w) * 16, (unsigned)(t + 1),
                           __ATOMIC_RELAXED, __HIP_MEMORY_SCOPE_AGENT);
      }
    }

    // out writes AFTER the flag (off the cross-WG critical path)
    if (act) {
      #pragma unroll
      for (int reg = 0; reg < 4; ++reg) {
        size_t bglob = (size_t)16 * g + 4 * lg + reg;
        out[(size_t)t * BH + bglob * HDIM + hcol] = hnv[reg];
        if (t == SLEN - 1) {
          out[HS + bglob * HDIM + hcol] = hnv[reg];
          out[HS + BH + bglob * HDIM + hcol] = cnv[reg];
        }
      }
    }
  }
}

extern "C" void kernel_launch(void* const* d_in, const int* in_sizes, int n_in,
                              void* d_out, int out_size, void* d_ws, size_t ws_size,
                              hipStream_t stream) {
  const float* x    = (const float*)d_in[0];
  const float* W    = (const float*)d_in[1];
  const float* U    = (const float*)d_in[2];
  const float* bias = (const float*)d_in[3];
  float* out = (float*)d_out;

  char* p = (char*)d_ws;
  unsigned short* CT    = (unsigned short*)p;                      p += (size_t)2048 * 1024 * 2;  // 4 MiB
  unsigned short* gring = (unsigned short*)p;                      p += (size_t)RING * BROWS * 2048 * 2; // 8 MiB
  unsigned short* hG    = (unsigned short*)p;                      p += (size_t)2 * BH * 2;       // 128 KiB
  unsigned* flags  = (unsigned*)p;                                 p += 4 * 16 * 16 * 4;          // 4 KiB
  unsigned* flags2 = (unsigned*)p;                                                               // 32 KiB

  hipMemsetAsync(flags, 0, (4 * 16 + RING * 16) * 16 * sizeof(unsigned), stream);
  prep_ct<<<1024, 256, 0, stream>>>(W, U, CT);
  lstm_fused<<<NTOT, NTHREADS, 128 * 1024, stream>>>(x, bias, CT, gring, hG, flags, flags2, out);
}

// Round 12
// 7329.492 us; speedup vs baseline: 4.3677x; 1.8295x over previous
//
#include <hip/hip_runtime.h>
#include <hip/hip_bf16.h>

#define SLEN 2048
#define BROWS 64
#define IDIM 512
#define HDIM 512
#define BH (BROWS * HDIM)
#define RING 32
#define NREC 64
#define NTOT 256
#define NTHREADS 512

typedef __bf16 bf16x8 __attribute__((ext_vector_type(8)));
typedef float  f32x4  __attribute__((ext_vector_type(4)));
typedef int    i32x4  __attribute__((ext_vector_type(4)));
typedef int    i32x2  __attribute__((ext_vector_type(2)));

__device__ inline unsigned short f2bf(float f) {
  union { float f; unsigned u; } v; v.f = f;
  unsigned r = v.u + 0x7FFFu + ((v.u >> 16) & 1u);
  return (unsigned short)(r >> 16);
}
__device__ inline float bf2f(unsigned short s) {
  union { unsigned u; float f; } v; v.u = ((unsigned)s) << 16;
  return v.f;
}
__device__ inline float sigm(float x) {
  return __builtin_amdgcn_rcpf(1.f + __expf(-x));
}
__device__ inline float tanh_f(float x) {
  float e = __expf(2.f * x);
  return 1.f - 2.f * __builtin_amdgcn_rcpf(e + 1.f);
}

// CT[row][k], row-major K=1024. row = w*128 + n*16 + gate*4 + hsub
//   where j = gate*512 + hcol, hcol = w*32 + n*4 + hsub
// k < 512: W[k][j] ; k >= 512: U[k-512][j]
__global__ __launch_bounds__(256) void prep_ct(const float* __restrict__ W,
                                               const float* __restrict__ U,
                                               unsigned short* __restrict__ CT) {
  int k = blockIdx.x;
  const float* src = (k < IDIM) ? (W + (size_t)k * 2048) : (U + (size_t)(k - IDIM) * 2048);
  for (int j = threadIdx.x; j < 2048; j += 256) {
    int gate = j >> 9, hcol = j & 511;
    int w = hcol >> 5, n = (hcol >> 2) & 7, hsub = hcol & 3;
    int row = w * 128 + n * 16 + gate * 4 + hsub;
    CT[(size_t)row * 1024 + k] = f2bf(src[j]);
  }
}

__global__ __launch_bounds__(NTHREADS)
void lstm_fused(const float* __restrict__ x, const float* __restrict__ bias,
                const unsigned short* __restrict__ CT,
                unsigned short* __restrict__ gring,  // [RING][64][2048] bf16
                unsigned short* __restrict__ hG,     // [2][64][512] bf16
                unsigned* __restrict__ flags,        // [4*16] stride-16 dwords
                unsigned* __restrict__ flags2,       // [RING*16] stride-16 dwords
                float* __restrict__ out) {
  const int bid  = blockIdx.x;
  const int tid  = threadIdx.x;
  const int lane = tid & 63;
  const int wid  = tid >> 6;           // 0..7
  const int lg   = lane >> 4;
  const int lc   = lane & 15;

  extern __shared__ char Udyn[];       // 128 KB: rec U slice (swizzled)
  __shared__ union {
    struct {
      unsigned short Ast[16 * 512];    // 16 KB h(t-1), swizzled
      unsigned short Gst[16 * 128];    // 4 KB gates_x slice
      unsigned short stag[16][32];     // 1 KB h slice (16 rows x 32 hcols)
    } r;
    unsigned short Gout[64 * 128];     // 16 KB worker gate staging
  } sm;

  // ================================================================
  // WORKER PATH: x@W + bias -> gring (bf16), striped over t
  // ================================================================
  if (bid >= NREC) {
    const int wid2 = bid - NREC;
    const int w2 = wid2 & 15;          // col split: gate-cols [128*w2, +128)
    const int s  = wid2 >> 4;          // t stripe 0..11
    const int rt = wid & 3;            // row tile: batch rows [16*rt, +16)
    const int ch = wid >> 2;           // col half: tiles 4*ch..4*ch+3

    float bias_v[4];
    #pragma unroll
    for (int c4 = 0; c4 < 4; ++c4) {
      int n2 = 4 * ch + c4;
      bias_v[c4] = bias[(lc >> 2) * 512 + w2 * 32 + n2 * 4 + (lc & 3)];
    }

    for (int t = s; t < SLEN; t += 12) {
      // backpressure: wave 0 only (store is gated by the syncthreads below)
      if (wid == 0 && t >= RING) {
        unsigned need = (unsigned)(t - RING + 2);
        const unsigned* bp = flags + (size_t)((lane & 3) * 16 + w2) * 16;
        while (__ballot((lane < 4) &&
                        (__hip_atomic_load(bp, __ATOMIC_RELAXED,
                                           __HIP_MEMORY_SCOPE_AGENT) < need)) != 0ull)
          __builtin_amdgcn_s_sleep(16);
      }

      f32x4 acc[4];
      #pragma unroll
      for (int c4 = 0; c4 < 4; ++c4)
        acc[c4] = (f32x4){bias_v[c4], bias_v[c4], bias_v[c4], bias_v[c4]};

      const float* xp = x + ((size_t)t * BROWS + 16 * rt + lc) * IDIM + lg * 8;
      #pragma unroll
      for (int kk = 0; kk < 16; ++kk) {
        f32x4 v0 = *(const f32x4*)(xp + kk * 32);
        f32x4 v1 = *(const f32x4*)(xp + kk * 32 + 4);
        bf16x8 a;
        #pragma unroll
        for (int j = 0; j < 4; ++j) { a[j] = (__bf16)v0[j]; a[4 + j] = (__bf16)v1[j]; }
        #pragma unroll
        for (int c4 = 0; c4 < 4; ++c4) {
          const bf16x8 b = *(const bf16x8*)(CT + (size_t)(w2 * 128 + (4 * ch + c4) * 16 + lc) * 1024
                                            + kk * 32 + lg * 8);
          acc[c4] = __builtin_amdgcn_mfma_f32_16x16x32_bf16(a, b, acc[c4], 0, 0, 0);
        }
      }

      // stage to LDS
      #pragma unroll
      for (int c4 = 0; c4 < 4; ++c4)
        #pragma unroll
        for (int reg = 0; reg < 4; ++reg)
          sm.Gout[(size_t)(16 * rt + 4 * lg + reg) * 128 + (4 * ch + c4) * 16 + lc]
            = f2bf(acc[c4][reg]);
      __syncthreads();   // also gates the store on wave 0's backpressure

      // coop store 16 KB -> ring slot (32B/thread, device scope)
      {
        int row = tid >> 3, cs = (tid & 7) * 16;          // 16 shorts = 32B
        const unsigned short* srcp = sm.Gout + (size_t)row * 128 + cs;
        i32x4 v0 = *(const i32x4*)srcp;
        i32x4 v1 = *(const i32x4*)(srcp + 8);
        unsigned short* d = gring + (size_t)(t & (RING - 1)) * (BROWS * 2048)
                          + (size_t)row * 2048 + w2 * 128 + cs;
        asm volatile("global_store_dwordx4 %0, %1, off sc1" :: "v"(d), "v"(v0) : "memory");
        asm volatile("global_store_dwordx4 %0, %1, off offset:16 sc1" :: "v"(d), "v"(v1) : "memory");
        asm volatile("s_waitcnt vmcnt(0)" ::: "memory");
      }
      __syncthreads();   // all threads drained -> flag release + Gout reuse safe
      if (tid == 0)
        __hip_atomic_store(flags2 + (size_t)((t & (RING - 1)) * 16 + w2) * 16,
                           (unsigned)(t + 1), __ATOMIC_RELAXED, __HIP_MEMORY_SCOPE_AGENT);
    }
    return;
  }

  // ================================================================
  // RECURRENT PATH: 64 WGs, 8 waves each, h@U from LDS weights
  // ================================================================
  const int g = bid & 3;               // batch rows [16g, 16g+16)
  const int w = bid >> 2;              // hcols [32w, 32w+32)
  const int n = wid;                   // col tile 0..7 (gate-cols n*16..+16)

  // cooperative U -> dynamic LDS (swizzled), 256B/thread
  #pragma unroll
  for (int i = 0; i < 16; ++i) {
    int idx16 = tid + NTHREADS * i;    // 0..8191
    int r = idx16 >> 6, c16 = idx16 & 63;
    i32x4 v = *(const i32x4*)(CT + (size_t)(w * 128 + r) * 1024 + 512 + c16 * 8);
    *(i32x4*)(Udyn + (size_t)r * 1024 + ((c16 * 16) ^ ((r & 7) << 4))) = v;
  }
  __syncthreads();

  float cst[4] = {0.f, 0.f, 0.f, 0.f};
  const bool act = (lc < 4);
  const int hcol = w * 32 + n * 4 + (lc & 3);
  const int sw = (lc & 7) << 4;
  const size_t HS = (size_t)SLEN * BH;

  for (int t = 0; t < SLEN; ++t) {
    // ---- single-poller: wave 0 watches h-flags (lanes 0-15) + gates flag (lane 16) ----
    if (wid == 0) {
      const unsigned* fpH = flags + (size_t)(g * 16 + (lane & 15)) * 16;
      const unsigned* fpG = flags2 + (size_t)((t & (RING - 1)) * 16 + w) * 16;
      int notok;
      do {
        int ok = 1;
        if (lane < 16) {
          if (t > 0)
            ok = (__hip_atomic_load(fpH, __ATOMIC_RELAXED,
                                    __HIP_MEMORY_SCOPE_AGENT) >= (unsigned)t);
        } else if (lane == 16) {
          ok = (__hip_atomic_load(fpG, __ATOMIC_RELAXED,
                                  __HIP_MEMORY_SCOPE_AGENT) > (unsigned)t);
        }
        notok = !ok;
      } while (__ballot(notok) != 0ull);
    }
    __syncthreads();   // everyone released; h + gates data valid at device scope
    __builtin_amdgcn_sched_barrier(0);

    // ---- coop loads (issued together, one wait): gates -> Gst, h(t-1) -> Ast ----
    {
      int grow = tid >> 5, gcs = (tid & 31) * 4;          // 8B per thread
      const unsigned short* gpG = gring + (size_t)(t & (RING - 1)) * (BROWS * 2048)
                                + ((size_t)16 * g + grow) * 2048 + w * 128 + gcs;
      i32x2 gv;
      i32x4 v0, v1;
      int r = 0, c16 = 0;
      if (t > 0) {
        int idx0 = tid * 2;
        r = idx0 >> 6; c16 = idx0 & 63;
        const unsigned short* gpH = hG + (size_t)((t - 1) & 1) * BH
                                  + ((size_t)16 * g + r) * HDIM + c16 * 8;
        asm volatile("global_load_dwordx4 %0, %2, off sc1\n\t"
                     "global_load_dwordx4 %1, %2, off offset:16 sc1"
                     : "=&v"(v0), "=&v"(v1) : "v"(gpH) : "memory");
      }
      asm volatile("global_load_dwordx2 %0, %1, off sc1" : "=&v"(gv) : "v"(gpG) : "memory");
      asm volatile("s_waitcnt vmcnt(0)" ::: "memory");
      if (t > 0) {
        int rs = (r & 7) << 4;
        char* rowb = (char*)sm.r.Ast + r * 1024;
        *(i32x4*)(rowb + ((c16 * 16) ^ rs)) = v0;
        *(i32x4*)(rowb + (((c16 + 1) * 16) ^ rs)) = v1;
      }
      *(i32x2*)(sm.r.Gst + (size_t)grow * 128 + gcs) = gv;
    }
    __syncthreads();

    // ---- GEMM: acc = gates_x + h @ U  (all from LDS) ----
    f32x4 acc;
    #pragma unroll
    for (int reg = 0; reg < 4; ++reg)
      acc[reg] = bf2f(sm.r.Gst[(size_t)(4 * lg + reg) * 128 + n * 16 + lc]);

    if (t > 0) {
      const char* Ab = (const char*)sm.r.Ast + (size_t)lc * 1024;
      const char* Bb = Udyn + (size_t)(n * 16 + lc) * 1024;
      #pragma unroll
      for (int kk = 0; kk < 16; ++kk) {
        int koff = kk * 64 + lg * 16;
        bf16x8 a = *(const bf16x8*)(Ab + (koff ^ sw));
        bf16x8 b = *(const bf16x8*)(Bb + (koff ^ sw));
        acc = __builtin_amdgcn_mfma_f32_16x16x32_bf16(a, b, acc, 0, 0, 0);
      }
    }

    // ---- gates -> c,h (gate = lc>>2, hsub = lc&3) ----
    float hnv[4], cnv[4];
    #pragma unroll
    for (int reg = 0; reg < 4; ++reg) {
      float own = acc[reg];
      float g4  = __shfl_xor(own, 4, 64);
      float g8  = __shfl_xor(own, 8, 64);
      float g12 = __shfl_xor(own, 12, 64);
      float it = sigm(own), ft = sigm(g4), gt = tanh_f(g8), ot = sigm(g12);
      float cn = ft * cst[reg] + it * gt;
      cst[reg] = cn;
      float hn = ot * tanh_f(cn);
      hnv[reg] = hn; cnv[reg] = cn;
      if (act) sm.r.stag[4 * lg + reg][n * 4 + (lc & 3)] = f2bf(hn);
    }
    __syncthreads();   // stag complete

    if (t + 1 < SLEN) {
      // ---- wave 0: store 16 full 64B lines, one drain, flag ----
      if (wid == 0) {
        int row = lane >> 2, ch4 = lane & 3;
        i32x4 hv = *(const i32x4*)((const char*)sm.r.stag + row * 64 + ch4 * 16);
        const unsigned short* d0 = hG + (size_t)(t & 1) * BH
                                 + ((size_t)16 * g + row) * HDIM + w * 32 + ch4 * 8;
        asm volatile("global_store_dwordx4 %0, %1, off sc1"
                     :: "v"(d0), "v"(hv) : "memory");
        asm volatile("s_waitcnt vmcnt(0)" ::: "memory");
        if (lane == 0)
          __hip_atomic_store(flags + (size_t)(g * 16 + w) * 16, (unsigned)(t + 1),
                             __ATOMIC_RELAXED, __HIP_MEMORY_SCOPE_AGENT);
      }
    }

    // ---- out writes AFTER the flag (off the cross-WG critical path) ----
    if (act) {
      #pragma unroll
      for (int reg = 0; reg < 4; ++reg) {
        size_t bglob = (size_t)16 * g + 4 * lg + reg;
        out[(size_t)t * BH + bglob * HDIM + hcol] = hnv[reg];
        if (t == SLEN - 1) {
          out[HS + bglob * HDIM + hcol] = hnv[reg];
          out[HS + BH + bglob * HDIM + hcol] = cnv[reg];
        }
      }
    }
  }
}

extern "C" void kernel_launch(void* const* d_in, const int* in_sizes, int n_in,
                              void* d_out, int out_size, void* d_ws, size_t ws_size,
                              hipStream_t stream) {
  const float* x    = (const float*)d_in[0];
  const float* W    = (const float*)d_in[1];
  const float* U    = (const float*)d_in[2];
  const float* bias = (const float*)d_in[3];
  float* out = (float*)d_out;

  char* p = (char*)d_ws;
  unsigned short* CT    = (unsigned short*)p;                      p += (size_t)2048 * 1024 * 2;  // 4 MiB
  unsigned short* gring = (unsigned short*)p;                      p += (size_t)RING * BROWS * 2048 * 2; // 8 MiB
  unsigned short* hG    = (unsigned short*)p;                      p += (size_t)2 * BH * 2;       // 128 KiB
  unsigned* flags  = (unsigned*)p;                                 p += 4 * 16 * 16 * 4;          // 4 KiB
  unsigned* flags2 = (unsigned*)p;                                                               // 32 KiB

  hipMemsetAsync(flags, 0, (4 * 16 + RING * 16) * 16 * sizeof(unsigned), stream);
  prep_ct<<<1024, 256, 0, stream>>>(W, U, CT);
  lstm_fused<<<NTOT, NTHREADS, 128 * 1024, stream>>>(x, bias, CT, gring, hG, flags, flags2, out);
}

// Round 13
// 6025.574 us; speedup vs baseline: 5.3128x; 1.2164x over previous
//
#include <hip/hip_runtime.h>
#include <hip/hip_bf16.h>

#define SLEN 2048
#define BROWS 64
#define IDIM 512
#define HDIM 512
#define BH (BROWS * HDIM)
#define RING 32
#define HRING 8
#define NREC 64
#define NTOT 256
#define NTHREADS 512

typedef __bf16 bf16x8 __attribute__((ext_vector_type(8)));
typedef float  f32x4  __attribute__((ext_vector_type(4)));
typedef int    i32x4  __attribute__((ext_vector_type(4)));
typedef int    i32x2  __attribute__((ext_vector_type(2)));

__device__ inline unsigned short f2bf(float f) {
  union { float f; unsigned u; } v; v.f = f;
  unsigned r = v.u + 0x7FFFu + ((v.u >> 16) & 1u);
  return (unsigned short)(r >> 16);
}
__device__ inline float bf2f(unsigned short s) {
  union { unsigned u; float f; } v; v.u = ((unsigned)s) << 16;
  return v.f;
}
__device__ inline float sigm(float x) {
  return __builtin_amdgcn_rcpf(1.f + __expf(-x));
}
__device__ inline float tanh_f(float x) {
  float e = __expf(2.f * x);
  return 1.f - 2.f * __builtin_amdgcn_rcpf(e + 1.f);
}

// CT[row][k], row-major K=1024. row = w*128 + n*16 + gate*4 + hsub
//   where j = gate*512 + hcol, hcol = w*32 + n*4 + hsub
// k < 512: W[k][j] ; k >= 512: U[k-512][j]
__global__ __launch_bounds__(256) void prep_ct(const float* __restrict__ W,
                                               const float* __restrict__ U,
                                               unsigned short* __restrict__ CT) {
  int k = blockIdx.x;
  const float* src = (k < IDIM) ? (W + (size_t)k * 2048) : (U + (size_t)(k - IDIM) * 2048);
  for (int j = threadIdx.x; j < 2048; j += 256) {
    int gate = j >> 9, hcol = j & 511;
    int w = hcol >> 5, n = (hcol >> 2) & 7, hsub = hcol & 3;
    int row = w * 128 + n * 16 + gate * 4 + hsub;
    CT[(size_t)row * 1024 + k] = f2bf(src[j]);
  }
}

__global__ __launch_bounds__(NTHREADS)
void lstm_fused(const float* __restrict__ x, const float* __restrict__ bias,
                const unsigned short* __restrict__ CT,
                unsigned short* __restrict__ gring,  // [RING][64][2048] bf16
                unsigned short* __restrict__ hG,     // [HRING][64][512] bf16, 0xFF-init
                unsigned* __restrict__ flags,        // [4*16] stride-16 (rec progress)
                unsigned* __restrict__ flags2,       // [RING*16] stride-16 (gates ready)
                float* __restrict__ out) {
  const int bid  = blockIdx.x;
  const int tid  = threadIdx.x;
  const int lane = tid & 63;
  const int wid  = tid >> 6;           // 0..7
  const int lg   = lane >> 4;
  const int lc   = lane & 15;

  extern __shared__ char Udyn[];       // 128 KB: rec U slice (swizzled)
  __shared__ union {
    struct {
      unsigned short Ast[16 * 512];    // 16 KB h(t-1), swizzled
      unsigned short Gst[16 * 128];    // 4 KB gates_x slice
      unsigned short stag[16][32];     // 1 KB h slice (16 rows x 32 hcols)
    } r;
    unsigned short Gout[64 * 128];     // 16 KB worker gate staging
  } sm;

  // ================================================================
  // WORKER PATH: x@W + bias -> gring (bf16), striped over t
  // ================================================================
  if (bid >= NREC) {
    const int wid2 = bid - NREC;
    const int w2 = wid2 & 15;          // col split: gate-cols [128*w2, +128)
    const int s  = wid2 >> 4;          // t stripe 0..11
    const int rt = wid & 3;            // row tile: batch rows [16*rt, +16)
    const int ch = wid >> 2;           // col half: tiles 4*ch..4*ch+3

    float bias_v[4];
    #pragma unroll
    for (int c4 = 0; c4 < 4; ++c4) {
      int n2 = 4 * ch + c4;
      bias_v[c4] = bias[(lc >> 2) * 512 + w2 * 32 + n2 * 4 + (lc & 3)];
    }

    for (int t = s; t < SLEN; t += 12) {
      // backpressure: wave 0 only (store is gated by the syncthreads below)
      if (wid == 0 && t >= RING) {
        unsigned need = (unsigned)(t - RING + 2);
        const unsigned* bp = flags + (size_t)((lane & 3) * 16 + w2) * 16;
        while (__ballot((lane < 4) &&
                        (__hip_atomic_load(bp, __ATOMIC_RELAXED,
                                           __HIP_MEMORY_SCOPE_AGENT) < need)) != 0ull)
          __builtin_amdgcn_s_sleep(16);
      }

      f32x4 acc[4];
      #pragma unroll
      for (int c4 = 0; c4 < 4; ++c4)
        acc[c4] = (f32x4){bias_v[c4], bias_v[c4], bias_v[c4], bias_v[c4]};

      const float* xp = x + ((size_t)t * BROWS + 16 * rt + lc) * IDIM + lg * 8;
      #pragma unroll
      for (int kk = 0; kk < 16; ++kk) {
        f32x4 v0 = *(const f32x4*)(xp + kk * 32);
        f32x4 v1 = *(const f32x4*)(xp + kk * 32 + 4);
        bf16x8 a;
        #pragma unroll
        for (int j = 0; j < 4; ++j) { a[j] = (__bf16)v0[j]; a[4 + j] = (__bf16)v1[j]; }
        #pragma unroll
        for (int c4 = 0; c4 < 4; ++c4) {
          const bf16x8 b = *(const bf16x8*)(CT + (size_t)(w2 * 128 + (4 * ch + c4) * 16 + lc) * 1024
                                            + kk * 32 + lg * 8);
          acc[c4] = __builtin_amdgcn_mfma_f32_16x16x32_bf16(a, b, acc[c4], 0, 0, 0);
        }
      }

      // stage to LDS
      #pragma unroll
      for (int c4 = 0; c4 < 4; ++c4)
        #pragma unroll
        for (int reg = 0; reg < 4; ++reg)
          sm.Gout[(size_t)(16 * rt + 4 * lg + reg) * 128 + (4 * ch + c4) * 16 + lc]
            = f2bf(acc[c4][reg]);
      __syncthreads();   // also gates the store on wave 0's backpressure

      // coop store 16 KB -> ring slot (32B/thread, device scope)
      {
        int row = tid >> 3, cs = (tid & 7) * 16;          // 16 shorts = 32B
        const unsigned short* srcp = sm.Gout + (size_t)row * 128 + cs;
        i32x4 v0 = *(const i32x4*)srcp;
        i32x4 v1 = *(const i32x4*)(srcp + 8);
        unsigned short* d = gring + (size_t)(t & (RING - 1)) * (BROWS * 2048)
                          + (size_t)row * 2048 + w2 * 128 + cs;
        asm volatile("global_store_dwordx4 %0, %1, off sc1" :: "v"(d), "v"(v0) : "memory");
        asm volatile("global_store_dwordx4 %0, %1, off offset:16 sc1" :: "v"(d), "v"(v1) : "memory");
        asm volatile("s_waitcnt vmcnt(0)" ::: "memory");
      }
      __syncthreads();   // all threads drained -> flag release + Gout reuse safe
      if (tid == 0)
        __hip_atomic_store(flags2 + (size_t)((t & (RING - 1)) * 16 + w2) * 16,
                           (unsigned)(t + 1), __ATOMIC_RELAXED, __HIP_MEMORY_SCOPE_AGENT);
    }
    return;
  }

  // ================================================================
  // RECURRENT PATH: 64 WGs, 8 waves each, h@U from LDS weights.
  // h exchange: fire&forget stores + per-thread sentinel poll (data IS flag).
  // ================================================================
  const int g = bid & 3;               // batch rows [16g, 16g+16)
  const int w = bid >> 2;              // hcols [32w, 32w+32)
  const int n = wid;                   // col tile 0..7 (gate-cols n*16..+16)

  // cooperative U -> dynamic LDS (swizzled), 256B/thread
  #pragma unroll
  for (int i = 0; i < 16; ++i) {
    int idx16 = tid + NTHREADS * i;    // 0..8191
    int r = idx16 >> 6, c16 = idx16 & 63;
    i32x4 v = *(const i32x4*)(CT + (size_t)(w * 128 + r) * 1024 + 512 + c16 * 8);
    *(i32x4*)(Udyn + (size_t)r * 1024 + ((c16 * 16) ^ ((r & 7) << 4))) = v;
  }
  __syncthreads();

  float cst[4] = {0.f, 0.f, 0.f, 0.f};
  const bool act = (lc < 4);
  const int hcol = w * 32 + n * 4 + (lc & 3);
  const size_t HS = (size_t)SLEN * BH;

  const int prow = tid >> 5;                 // 0..15: my staged row
  const int pc16 = (tid * 2) & 63;           // my first 16B chunk in the row

  for (int t = 0; t < SLEN; ++t) {
    // ---- phase 1: gates-ready check (broadcast load, 1 txn/wave; workers ahead) ----
    {
      const unsigned* fpG = flags2 + (size_t)((t & (RING - 1)) * 16 + w) * 16;
      while (__ballot(__hip_atomic_load(fpG, __ATOMIC_RELAXED,
                                        __HIP_MEMORY_SCOPE_AGENT)
                      <= (unsigned)t) != 0ull) {}
    }

    // ---- phase 2: issue gates load; sentinel-poll own 32B of h(t-1) ----
    i32x2 gv;
    {
      const unsigned short* gpG = gring + (size_t)(t & (RING - 1)) * (BROWS * 2048)
                                + ((size_t)16 * g + prow) * 2048 + w * 128 + (tid & 31) * 4;
      asm volatile("global_load_dwordx2 %0, %1, off sc1" : "=&v"(gv) : "v"(gpG) : "memory");
    }
    if (t > 0) {
      const unsigned short* hp = hG + (size_t)((t - 1) & (HRING - 1)) * BH
                               + ((size_t)16 * g + prow) * HDIM + pc16 * 8;
      i32x4 v0, v1;
      int bad;
      do {
        asm volatile("global_load_dwordx4 %0, %2, off sc1\n\t"
                     "global_load_dwordx4 %1, %2, off offset:16 sc1\n\t"
                     "s_waitcnt vmcnt(0)"
                     : "=&v"(v0), "=&v"(v1) : "v"(hp) : "memory");
        bad = 0;
        #pragma unroll
        for (int j = 0; j < 4; ++j) {
          unsigned a = (unsigned)v0[j], b = (unsigned)v1[j];
          bad |= (int)(((a & 0xFFFFu) == 0xFFFFu) | ((a >> 16) == 0xFFFFu)
                     | ((b & 0xFFFFu) == 0xFFFFu) | ((b >> 16) == 0xFFFFu));
        }
      } while (bad);
      int rs = (prow & 7) << 4;
      char* rowb = (char*)sm.r.Ast + prow * 1024;
      *(i32x4*)(rowb + ((pc16 * 16) ^ rs)) = v0;
      *(i32x4*)(rowb + (((pc16 + 1) * 16) ^ rs)) = v1;
    } else {
      asm volatile("s_waitcnt vmcnt(0)" ::: "memory");
    }
    *(i32x2*)(sm.r.Gst + (size_t)prow * 128 + (tid & 31) * 4) = gv;

    // progress flag for worker backpressure: gring(t) read is drained
    if (wid == 0 && lane == 0)
      __hip_atomic_store(flags + (size_t)(g * 16 + w) * 16, (unsigned)(t + 1),
                         __ATOMIC_RELAXED, __HIP_MEMORY_SCOPE_AGENT);

    // reset my written 1KB of slot (t-2): sentinel success for h(t-1) proves
    // all peers produced h(t-1), hence fully consumed h(t-2). Fire&forget;
    // drained by my next-step vmcnt(0) before any causal rewrite (HRING=8).
    if (wid == 0 && t >= 2) {
      int row = lane >> 2, ch4 = lane & 3;
      unsigned short* dr = hG + (size_t)((t - 2) & (HRING - 1)) * BH
                         + ((size_t)16 * g + row) * HDIM + w * 32 + ch4 * 8;
      i32x4 ff = {-1, -1, -1, -1};
      asm volatile("global_store_dwordx4 %0, %1, off sc1" :: "v"(dr), "v"(ff) : "memory");
    }
    __syncthreads();   // Ast + Gst staged

    // ---- GEMM: acc = gates_x + h @ U  (all from LDS) ----
    f32x4 acc;
    #pragma unroll
    for (int reg = 0; reg < 4; ++reg)
      acc[reg] = bf2f(sm.r.Gst[(size_t)(4 * lg + reg) * 128 + n * 16 + lc]);

    if (t > 0) {
      const int sw = (lc & 7) << 4;
      const char* Ab = (const char*)sm.r.Ast + (size_t)lc * 1024;
      const char* Bb = Udyn + (size_t)(n * 16 + lc) * 1024;
      #pragma unroll
      for (int kk = 0; kk < 16; ++kk) {
        int koff = kk * 64 + lg * 16;
        bf16x8 a = *(const bf16x8*)(Ab + (koff ^ sw));
        bf16x8 b = *(const bf16x8*)(Bb + (koff ^ sw));
        acc = __builtin_amdgcn_mfma_f32_16x16x32_bf16(a, b, acc, 0, 0, 0);
      }
    }

    // ---- gates -> c,h (gate = lc>>2, hsub = lc&3) ----
    float hnv[4], cnv[4];
    #pragma unroll
    for (int reg = 0; reg < 4; ++reg) {
      float own = acc[reg];
      float g4  = __shfl_xor(own, 4, 64);
      float g8  = __shfl_xor(own, 8, 64);
      float g12 = __shfl_xor(own, 12, 64);
      float it = sigm(own), ft = sigm(g4), gt = tanh_f(g8), ot = sigm(g12);
      float cn = ft * cst[reg] + it * gt;
      cst[reg] = cn;
      float hn = ot * tanh_f(cn);
      hnv[reg] = hn; cnv[reg] = cn;
      if (act) sm.r.stag[4 * lg + reg][n * 4 + (lc & 3)] = f2bf(hn);
    }
    __syncthreads();   // stag complete

    // ---- h(t) store: wave 0, 16 full 64B lines, FIRE & FORGET (no drain!) ----
    if (t + 1 < SLEN && wid == 0) {
      int row = lane >> 2, ch4 = lane & 3;
      i32x4 hv = *(const i32x4*)((const char*)sm.r.stag + row * 64 + ch4 * 16);
      const unsigned short* d0 = hG + (size_t)(t & (HRING - 1)) * BH
                               + ((size_t)16 * g + row) * HDIM + w * 32 + ch4 * 8;
      asm volatile("global_store_dwordx4 %0, %1, off sc1"
                   :: "v"(d0), "v"(hv) : "memory");
    }

    // ---- out writes (off the cross-WG critical path) ----
    if (act) {
      #pragma unroll
      for (int reg = 0; reg < 4; ++reg) {
        size_t bglob = (size_t)16 * g + 4 * lg + reg;
        out[(size_t)t * BH + bglob * HDIM + hcol] = hnv[reg];
        if (t == SLEN - 1) {
          out[HS + bglob * HDIM + hcol] = hnv[reg];
          out[HS + BH + bglob * HDIM + hcol] = cnv[reg];
        }
      }
    }
  }
}

extern "C" void kernel_launch(void* const* d_in, const int* in_sizes, int n_in,
                              void* d_out, int out_size, void* d_ws, size_t ws_size,
                              hipStream_t stream) {
  const float* x    = (const float*)d_in[0];
  const float* W    = (const float*)d_in[1];
  const float* U    = (const float*)d_in[2];
  const float* bias = (const float*)d_in[3];
  float* out = (float*)d_out;

  char* p = (char*)d_ws;
  unsigned short* CT    = (unsigned short*)p;  p += (size_t)2048 * 1024 * 2;        // 4 MiB
  unsigned short* gring = (unsigned short*)p;  p += (size_t)RING * BROWS * 2048 * 2; // 8 MiB
  unsigned short* hG    = (unsigned short*)p;  p += (size_t)HRING * BH * 2;          // 512 KiB
  unsigned* flags  = (unsigned*)p;             p += 4 * 16 * 16 * 4;                 // 4 KiB
  unsigned* flags2 = (unsigned*)p;                                                   // 32 KiB

  hipMemsetAsync(hG, 0xFF, (size_t)HRING * BH * 2, stream);
  hipMemsetAsync(flags, 0, (4 * 16 + RING * 16) * 16 * sizeof(unsigned), stream);
  prep_ct<<<1024, 256, 0, stream>>>(W, U, CT);
  lstm_fused<<<NTOT, NTHREADS, 128 * 1024, stream>>>(x, bias, CT, gring, hG, flags, flags2, out);
}

// Round 14
// 5953.161 us; speedup vs baseline: 5.3774x; 1.0122x over previous
//
#include <hip/hip_runtime.h>
#include <hip/hip_bf16.h>

#define SLEN 2048
#define BROWS 64
#define IDIM 512
#define HDIM 512
#define BH (BROWS * HDIM)
#define RING 32
#define HRING 8
#define NREC 64
#define NTOT 256
#define NTHREADS 512

typedef __bf16 bf16x8 __attribute__((ext_vector_type(8)));
typedef float  f32x4  __attribute__((ext_vector_type(4)));
typedef int    i32x4  __attribute__((ext_vector_type(4)));
typedef int    i32x2  __attribute__((ext_vector_type(2)));

__device__ inline unsigned short f2bf(float f) {
  union { float f; unsigned u; } v; v.f = f;
  unsigned r = v.u + 0x7FFFu + ((v.u >> 16) & 1u);
  return (unsigned short)(r >> 16);
}
__device__ inline float bf2f(unsigned short s) {
  union { unsigned u; float f; } v; v.u = ((unsigned)s) << 16;
  return v.f;
}
__device__ inline float sigm(float x) {
  return __builtin_amdgcn_rcpf(1.f + __expf(-x));
}
__device__ inline float tanh_f(float x) {
  float e = __expf(2.f * x);
  return 1.f - 2.f * __builtin_amdgcn_rcpf(e + 1.f);
}

// CT[row][k], row-major K=1024. row = w*128 + n*16 + gate*4 + hsub
//   where j = gate*512 + hcol, hcol = w*32 + n*4 + hsub
// k < 512: W[k][j] ; k >= 512: U[k-512][j]
__global__ __launch_bounds__(256) void prep_ct(const float* __restrict__ W,
                                               const float* __restrict__ U,
                                               unsigned short* __restrict__ CT) {
  int k = blockIdx.x;
  const float* src = (k < IDIM) ? (W + (size_t)k * 2048) : (U + (size_t)(k - IDIM) * 2048);
  for (int j = threadIdx.x; j < 2048; j += 256) {
    int gate = j >> 9, hcol = j & 511;
    int w = hcol >> 5, n = (hcol >> 2) & 7, hsub = hcol & 3;
    int row = w * 128 + n * 16 + gate * 4 + hsub;
    CT[(size_t)row * 1024 + k] = f2bf(src[j]);
  }
}

__global__ __launch_bounds__(NTHREADS)
void lstm_fused(const float* __restrict__ x, const float* __restrict__ bias,
                const unsigned short* __restrict__ CT,
                unsigned short* __restrict__ gring,  // [RING][64][2048] bf16
                unsigned short* __restrict__ hG,     // [HRING][64][512] bf16, 0xFF-init
                unsigned* __restrict__ flags,        // [4*16] stride-16 (rec progress)
                unsigned* __restrict__ flags2,       // [RING*16] stride-16 (gates ready)
                float* __restrict__ out) {
  const int bid  = blockIdx.x;
  const int tid  = threadIdx.x;
  const int lane = tid & 63;
  const int wid  = tid >> 6;           // 0..7
  const int lg   = lane >> 4;
  const int lc   = lane & 15;

  extern __shared__ char Udyn[];       // 128 KB: rec U slice (swizzled)
  __shared__ union {
    struct {
      unsigned short Ast[16 * 512];    // 16 KB h(t-1), swizzled
      unsigned short Gst[2][16 * 128]; // 8 KB gates_x, double-buffered
      unsigned short stag[16][32];     // 1 KB h slice (16 rows x 32 hcols)
    } r;
    unsigned short Gout[64 * 128];     // 16 KB worker gate staging
  } sm;

  // ================================================================
  // WORKER PATH: x@W + bias -> gring (bf16), striped over t
  // ================================================================
  if (bid >= NREC) {
    const int wid2 = bid - NREC;
    const int w2 = wid2 & 15;          // col split: gate-cols [128*w2, +128)
    const int s  = wid2 >> 4;          // t stripe 0..11
    const int rt = wid & 3;            // row tile: batch rows [16*rt, +16)
    const int ch = wid >> 2;           // col half: tiles 4*ch..4*ch+3

    float bias_v[4];
    #pragma unroll
    for (int c4 = 0; c4 < 4; ++c4) {
      int n2 = 4 * ch + c4;
      bias_v[c4] = bias[(lc >> 2) * 512 + w2 * 32 + n2 * 4 + (lc & 3)];
    }

    for (int t = s; t < SLEN; t += 12) {
      // backpressure: wave 0 only (store is gated by the syncthreads below)
      if (wid == 0 && t >= RING) {
        unsigned need = (unsigned)(t - RING + 2);
        const unsigned* bp = flags + (size_t)((lane & 3) * 16 + w2) * 16;
        while (__ballot((lane < 4) &&
                        (__hip_atomic_load(bp, __ATOMIC_RELAXED,
                                           __HIP_MEMORY_SCOPE_AGENT) < need)) != 0ull)
          __builtin_amdgcn_s_sleep(16);
      }

      f32x4 acc[4];
      #pragma unroll
      for (int c4 = 0; c4 < 4; ++c4)
        acc[c4] = (f32x4){bias_v[c4], bias_v[c4], bias_v[c4], bias_v[c4]};

      const float* xp = x + ((size_t)t * BROWS + 16 * rt + lc) * IDIM + lg * 8;
      #pragma unroll
      for (int kk = 0; kk < 16; ++kk) {
        f32x4 v0 = *(const f32x4*)(xp + kk * 32);
        f32x4 v1 = *(const f32x4*)(xp + kk * 32 + 4);
        bf16x8 a;
        #pragma unroll
        for (int j = 0; j < 4; ++j) { a[j] = (__bf16)v0[j]; a[4 + j] = (__bf16)v1[j]; }
        #pragma unroll
        for (int c4 = 0; c4 < 4; ++c4) {
          const bf16x8 b = *(const bf16x8*)(CT + (size_t)(w2 * 128 + (4 * ch + c4) * 16 + lc) * 1024
                                            + kk * 32 + lg * 8);
          acc[c4] = __builtin_amdgcn_mfma_f32_16x16x32_bf16(a, b, acc[c4], 0, 0, 0);
        }
      }

      // stage to LDS
      #pragma unroll
      for (int c4 = 0; c4 < 4; ++c4)
        #pragma unroll
        for (int reg = 0; reg < 4; ++reg)
          sm.Gout[(size_t)(16 * rt + 4 * lg + reg) * 128 + (4 * ch + c4) * 16 + lc]
            = f2bf(acc[c4][reg]);
      __syncthreads();   // also gates the store on wave 0's backpressure

      // coop store 16 KB -> ring slot (32B/thread, device scope)
      {
        int row = tid >> 3, cs = (tid & 7) * 16;          // 16 shorts = 32B
        const unsigned short* srcp = sm.Gout + (size_t)row * 128 + cs;
        i32x4 v0 = *(const i32x4*)srcp;
        i32x4 v1 = *(const i32x4*)(srcp + 8);
        unsigned short* d = gring + (size_t)(t & (RING - 1)) * (BROWS * 2048)
                          + (size_t)row * 2048 + w2 * 128 + cs;
        asm volatile("global_store_dwordx4 %0, %1, off sc1" :: "v"(d), "v"(v0) : "memory");
        asm volatile("global_store_dwordx4 %0, %1, off offset:16 sc1" :: "v"(d), "v"(v1) : "memory");
        asm volatile("s_waitcnt vmcnt(0)" ::: "memory");
      }
      __syncthreads();   // all threads drained -> flag release + Gout reuse safe
      if (tid == 0)
        __hip_atomic_store(flags2 + (size_t)((t & (RING - 1)) * 16 + w2) * 16,
                           (unsigned)(t + 1), __ATOMIC_RELAXED, __HIP_MEMORY_SCOPE_AGENT);
    }
    return;
  }

  // ================================================================
  // RECURRENT PATH: 64 WGs, 8 waves each, h@U from LDS weights.
  // Fused single poll per step: {flag2(t+1), gring(t+1), h(t-1) sentinel}.
  // ================================================================
  const int g = bid & 3;               // batch rows [16g, 16g+16)
  const int w = bid >> 2;              // hcols [32w, 32w+32)
  const int n = wid;                   // col tile 0..7 (gate-cols n*16..+16)

  // cooperative U -> dynamic LDS (swizzled), 256B/thread
  #pragma unroll
  for (int i = 0; i < 16; ++i) {
    int idx16 = tid + NTHREADS * i;    // 0..8191
    int r = idx16 >> 6, c16 = idx16 & 63;
    i32x4 v = *(const i32x4*)(CT + (size_t)(w * 128 + r) * 1024 + 512 + c16 * 8);
    *(i32x4*)(Udyn + (size_t)r * 1024 + ((c16 * 16) ^ ((r & 7) << 4))) = v;
  }

  const int prow = tid >> 5;                 // 0..15: my staged row
  const int pcol = (tid & 31) * 4;           // my 4-short chunk in gring row
  const int pc16 = (tid * 2) & 63;           // my first 16B chunk in hG row

  // ---- prologue: fetch gring(0) -> Gst[0] ----
  {
    const unsigned* fpG = flags2 + (size_t)(0 * 16 + w) * 16;
    const unsigned short* gpG = gring + ((size_t)16 * g + prow) * 2048 + w * 128 + pcol;
    unsigned f2v; i32x2 gv;
    do {
      asm volatile("global_load_dword %0, %2, off sc1\n\t"
                   "global_load_dwordx2 %1, %3, off sc1\n\t"
                   "s_waitcnt vmcnt(0)"
                   : "=&v"(f2v), "=&v"(gv) : "v"(fpG), "v"(gpG) : "memory");
    } while (f2v == 0u);
    *(i32x2*)(&sm.r.Gst[0][(size_t)prow * 128 + pcol]) = gv;
  }
  __syncthreads();

  float cst[4] = {0.f, 0.f, 0.f, 0.f};
  const bool act = (lc < 4);
  const int hcol = w * 32 + n * 4 + (lc & 3);
  const size_t HS = (size_t)SLEN * BH;

  for (int t = 0; t < SLEN; ++t) {
    // ---- fused poll: flag2(t+1) + gring(t+1) + h(t-1) sentinel, one vmcnt ----
    {
      const int s = t + 1;
      const bool ng = (s < SLEN);
      const unsigned* fpG = flags2 + (size_t)((s & (RING - 1)) * 16 + w) * 16;
      const unsigned short* gpG = gring + (size_t)(s & (RING - 1)) * (BROWS * 2048)
                                + ((size_t)16 * g + prow) * 2048 + w * 128 + pcol;
      const unsigned short* hp = hG + (size_t)((t - 1) & (HRING - 1)) * BH
                               + ((size_t)16 * g + prow) * HDIM + pc16 * 8;
      unsigned f2v = 0u; i32x2 gv; i32x4 v0, v1;
      int bad;
      do {
        if (ng)
          asm volatile("global_load_dword %0, %2, off sc1\n\t"
                       "global_load_dwordx2 %1, %3, off sc1"
                       : "=&v"(f2v), "=&v"(gv) : "v"(fpG), "v"(gpG) : "memory");
        if (t > 0)
          asm volatile("global_load_dwordx4 %0, %2, off sc1\n\t"
                       "global_load_dwordx4 %1, %2, off offset:16 sc1\n\t"
                       "s_waitcnt vmcnt(0)"
                       : "=&v"(v0), "=&v"(v1) : "v"(hp) : "memory");
        else
          asm volatile("s_waitcnt vmcnt(0)" ::: "memory");
        bad = 0;
        if (t > 0) {
          #pragma unroll
          for (int j = 0; j < 4; ++j) {
            unsigned a = (unsigned)v0[j], b = (unsigned)v1[j];
            bad |= (int)(((a & 0xFFFFu) == 0xFFFFu) | ((a >> 16) == 0xFFFFu)
                       | ((b & 0xFFFFu) == 0xFFFFu) | ((b >> 16) == 0xFFFFu));
          }
        }
        if (ng) bad |= (int)(f2v <= (unsigned)s);
      } while (bad);

      if (t > 0) {
        int rs = (prow & 7) << 4;
        char* rowb = (char*)sm.r.Ast + prow * 1024;
        *(i32x4*)(rowb + ((pc16 * 16) ^ rs)) = v0;
        *(i32x4*)(rowb + (((pc16 + 1) * 16) ^ rs)) = v1;
      }
      if (ng) *(i32x2*)(&sm.r.Gst[s & 1][(size_t)prow * 128 + pcol]) = gv;
    }

    // progress flag: gring(t+1) read drained -> workers may recycle old slots
    if (wid == 0 && lane == 0)
      __hip_atomic_store(flags + (size_t)(g * 16 + w) * 16, (unsigned)(t + 2),
                         __ATOMIC_RELAXED, __HIP_MEMORY_SCOPE_AGENT);

    // reset my written 1KB of slot (t-2): sentinel success for h(t-1) proves
    // all peers produced h(t-1), hence fully consumed h(t-2). Fire&forget;
    // drained by next-step vmcnt(0) long before causal rewrite (HRING=8).
    if (wid == 0 && t >= 2) {
      int row = lane >> 2, ch4 = lane & 3;
      unsigned short* dr = hG + (size_t)((t - 2) & (HRING - 1)) * BH
                         + ((size_t)16 * g + row) * HDIM + w * 32 + ch4 * 8;
      i32x4 ff = {-1, -1, -1, -1};
      asm volatile("global_store_dwordx4 %0, %1, off sc1" :: "v"(dr), "v"(ff) : "memory");
    }
    __syncthreads();   // Ast + Gst[(t+1)&1] staged

    // ---- GEMM: acc = gates_x + h @ U  (all from LDS) ----
    f32x4 acc;
    #pragma unroll
    for (int reg = 0; reg < 4; ++reg)
      acc[reg] = bf2f(sm.r.Gst[t & 1][(size_t)(4 * lg + reg) * 128 + n * 16 + lc]);

    if (t > 0) {
      const int sw = (lc & 7) << 4;
      const char* Ab = (const char*)sm.r.Ast + (size_t)lc * 1024;
      const char* Bb = Udyn + (size_t)(n * 16 + lc) * 1024;
      #pragma unroll
      for (int kk = 0; kk < 16; ++kk) {
        int koff = kk * 64 + lg * 16;
        bf16x8 a = *(const bf16x8*)(Ab + (koff ^ sw));
        bf16x8 b = *(const bf16x8*)(Bb + (koff ^ sw));
        acc = __builtin_amdgcn_mfma_f32_16x16x32_bf16(a, b, acc, 0, 0, 0);
      }
    }

    // ---- gates -> c,h (gate = lc>>2, hsub = lc&3) ----
    float hnv[4], cnv[4];
    #pragma unroll
    for (int reg = 0; reg < 4; ++reg) {
      float own = acc[reg];
      float g4  = __shfl_xor(own, 4, 64);
      float g8  = __shfl_xor(own, 8, 64);
      float g12 = __shfl_xor(own, 12, 64);
      float it = sigm(own), ft = sigm(g4), gt = tanh_f(g8), ot = sigm(g12);
      float cn = ft * cst[reg] + it * gt;
      cst[reg] = cn;
      float hn = ot * tanh_f(cn);
      hnv[reg] = hn; cnv[reg] = cn;
      if (act) sm.r.stag[4 * lg + reg][n * 4 + (lc & 3)] = f2bf(hn);
    }
    __syncthreads();   // stag complete

    // ---- h(t) store: wave 0, 16 full 64B lines, fire & forget ----
    if (t + 1 < SLEN && wid == 0) {
      int row = lane >> 2, ch4 = lane & 3;
      i32x4 hv = *(const i32x4*)((const char*)sm.r.stag + row * 64 + ch4 * 16);
      const unsigned short* d0 = hG + (size_t)(t & (HRING - 1)) * BH
                               + ((size_t)16 * g + row) * HDIM + w * 32 + ch4 * 8;
      asm volatile("global_store_dwordx4 %0, %1, off sc1"
                   :: "v"(d0), "v"(hv) : "memory");
    }

    // ---- out writes (off the cross-WG critical path) ----
    if (act) {
      #pragma unroll
      for (int reg = 0; reg < 4; ++reg) {
        size_t bglob = (size_t)16 * g + 4 * lg + reg;
        out[(size_t)t * BH + bglob * HDIM + hcol] = hnv[reg];
        if (t == SLEN - 1) {
          out[HS + bglob * HDIM + hcol] = hnv[reg];
          out[HS + BH + bglob * HDIM + hcol] = cnv[reg];
        }
      }
    }
  }
}

extern "C" void kernel_launch(void* const* d_in, const int* in_sizes, int n_in,
                              void* d_out, int out_size, void* d_ws, size_t ws_size,
                              hipStream_t stream) {
  const float* x    = (const float*)d_in[0];
  const float* W    = (const float*)d_in[1];
  const float* U    = (const float*)d_in[2];
  const float* bias = (const float*)d_in[3];
  float* out = (float*)d_out;

  char* p = (char*)d_ws;
  unsigned short* CT    = (unsigned short*)p;  p += (size_t)2048 * 1024 * 2;        // 4 MiB
  unsigned short* gring = (unsigned short*)p;  p += (size_t)RING * BROWS * 2048 * 2; // 8 MiB
  unsigned short* hG    = (unsigned short*)p;  p += (size_t)HRING * BH * 2;          // 512 KiB
  unsigned* flags  = (unsigned*)p;             p += 4 * 16 * 16 * 4;                 // 4 KiB
  unsigned* flags2 = (unsigned*)p;                                                   // 32 KiB

  hipMemsetAsync(hG, 0xFF, (size_t)HRING * BH * 2, stream);
  hipMemsetAsync(flags, 0, (4 * 16 + RING * 16) * 16 * sizeof(unsigned), stream);
  prep_ct<<<1024, 256, 0, stream>>>(W, U, CT);
  lstm_fused<<<NTOT, NTHREADS, 128 * 1024, stream>>>(x, bias, CT, gring, hG, flags, flags2, out);
}